// Round 2
// 1403.709 us; speedup vs baseline: 1.0086x; 1.0086x over previous
//
#include <hip/hip_runtime.h>
#include <cstdint>
#include <cstddef>

#define BBATCH 32
#define TT 14
#define MM 2048
#define QD 768
#define NHEAD 12
#define HD 64
#define FFD 3072
#define KVD 1024

typedef short bf16x8 __attribute__((ext_vector_type(8)));
typedef float f32x4 __attribute__((ext_vector_type(4)));

__device__ __forceinline__ uint16_t f2b(float f) {
  union { float f; uint32_t u; } v; v.f = f;
  uint32_t r = v.u + 0x7fffu + ((v.u >> 16) & 1u);
  return (uint16_t)(r >> 16);
}
__device__ __forceinline__ float b2f(uint16_t b) {
  union { uint32_t u; float f; } v; v.u = ((uint32_t)b) << 16; return v.f;
}

__device__ __forceinline__ void glds16(const void* g, void* l) {
  __builtin_amdgcn_global_load_lds(
      (const __attribute__((address_space(1))) void*)g,
      (__attribute__((address_space(3))) void*)l, 16, 0, 0);
}

// ---------------- cast f32 -> bf16, 8 elems/thread ----------------
__global__ void k_cast8(const float4* __restrict__ in, uint4* __restrict__ out) {
  int i = blockIdx.x * blockDim.x + threadIdx.x;
  float4 a = in[2 * i], b = in[2 * i + 1];
  uint4 o;
  o.x = (uint32_t)f2b(a.x) | ((uint32_t)f2b(a.y) << 16);
  o.y = (uint32_t)f2b(a.z) | ((uint32_t)f2b(a.w) << 16);
  o.z = (uint32_t)f2b(b.x) | ((uint32_t)f2b(b.y) << 16);
  o.w = (uint32_t)f2b(b.z) | ((uint32_t)f2b(b.w) << 16);
  out[i] = o;
}

// ------------- transpose-convert: in f32 [bz][R][C] -> out bf16 [bz][C][R] -------------
__global__ void k_transpose_bf16(const float* __restrict__ in, uint16_t* __restrict__ out,
                                 int R, int C) {
  __shared__ float tile[32][33];
  int bz = blockIdx.z;
  int c0 = blockIdx.x * 32, r0 = blockIdx.y * 32;
  int tx = threadIdx.x & 31, ty = threadIdx.x >> 5;  // 32 x 8
  const float* inb = in + (size_t)bz * R * C;
  uint16_t* outb = out + (size_t)bz * R * C;
#pragma unroll
  for (int rr = 0; rr < 32; rr += 8)
    tile[ty + rr][tx] = inb[(size_t)(r0 + ty + rr) * C + c0 + tx];
  __syncthreads();
#pragma unroll
  for (int rr = 0; rr < 32; rr += 8)
    outb[(size_t)(c0 + ty + rr) * R + r0 + tx] = f2b(tile[tx][ty + rr]);
}

__global__ void k_bias_concat(const float* __restrict__ bK, const float* __restrict__ bV,
                              float* __restrict__ out) {
  int i = blockIdx.x * 256 + threadIdx.x;  // 1536
  out[i] = (i < QD) ? bK[i] : bV[i - QD];
}

// ---------------- KV projection GEMM: 128x128 tiles, writes head-major K and transposed V ---
// A [65536][1024] bf16 (row = b*2048+m), Bt [1536][1024] bf16.
// K part (col<768):  Kh[b][h][m][64]   (h = col/64, d = col%64)
// V part (col>=768): Vt[b][h][d][2048] (h = (col-768)/64, d = (col-768)%64)
// Depth-2 pipelined staging: 3 LDS buffers, counted vmcnt(4), one raw barrier per K-step.
// Safety: stage(t+2) writes buf[(t+2)%3]; its last readers ran at compute(t-1), which
// precedes the iter-t barrier in every wave's program order. compute(t) reads buf[t%3],
// whose loads each wave confirmed complete via vmcnt(4) BEFORE that same barrier
// (wait-then-barrier). No other VMEM ops exist inside the loop, so the counts are exact.
__global__ __launch_bounds__(256) void k_gemm_kv(
    const uint16_t* __restrict__ A, const uint16_t* __restrict__ Bt,
    const float* __restrict__ bias, uint16_t* __restrict__ Kh, uint16_t* __restrict__ Vt) {
  __shared__ __align__(16) uint16_t As[3 * 4096];
  __shared__ __align__(16) uint16_t Bs[3 * 4096];
  const int K = KVD;
  int tid = threadIdx.x;
  int w = tid >> 6, l = tid & 63;

  // XCD-aware bijective swizzle: nwg = 12*512 = 6144, 6144 % 8 == 0.
  // XCD k gets 768 contiguous swz ids = 64 contiguous M-panels x all 12 N-tiles:
  // each A panel fetched by exactly one XCD; B (3 MB) stays L2-resident per XCD.
  int wgid = blockIdx.y * 12 + blockIdx.x;
  int swz = (wgid & 7) * 768 + (wgid >> 3);
  int bx = swz % 12, by = swz / 12;
  int m0 = by * 128, n0 = bx * 128;
  int wm = (w >> 1) * 64, wn = (w & 1) * 64;

  f32x4 zero4 = {0.f, 0.f, 0.f, 0.f};
  f32x4 acc[4][4];
#pragma unroll
  for (int i = 0; i < 4; i++)
#pragma unroll
    for (int j = 0; j < 4; j++) acc[i][j] = zero4;

  int sr = tid >> 2;
  int sc = (tid & 3) * 8;
  const uint16_t* gA0 = A + (size_t)(m0 + sr) * K + sc;
  const uint16_t* gA1 = A + (size_t)(m0 + 64 + sr) * K + sc;
  const uint16_t* gB0 = Bt + (size_t)(n0 + sr) * K + sc;
  const uint16_t* gB1 = Bt + (size_t)(n0 + 64 + sr) * K + sc;

  int lm = l & 15, q = l >> 4;

  auto stage = [&](int buf, int kt) {
    uint16_t* a = As + buf * 4096 + w * 512;
    uint16_t* b = Bs + buf * 4096 + w * 512;
    glds16(gA0 + kt, a);
    glds16(gA1 + kt, a + 2048);
    glds16(gB0 + kt, b);
    glds16(gB1 + kt, b + 2048);
  };
  auto compute = [&](int buf) {
    const uint16_t* as = As + buf * 4096;
    const uint16_t* bs = Bs + buf * 4096;
    bf16x8 af[4], bfv[4];
#pragma unroll
    for (int i = 0; i < 4; i++) {
      af[i] = *(const bf16x8*)&as[(wm + i * 16 + lm) * 32 + q * 8];
      bfv[i] = *(const bf16x8*)&bs[(wn + i * 16 + lm) * 32 + q * 8];
    }
#pragma unroll
    for (int i = 0; i < 4; i++)
#pragma unroll
      for (int j = 0; j < 4; j++)
        acc[i][j] = __builtin_amdgcn_mfma_f32_16x16x32_bf16(af[i], bfv[j], acc[i][j], 0, 0, 0);
  };

  const int NT = K / 32;  // 32
  stage(0, 0);
  stage(1, 32);
  int cur = 0;
  for (int t = 0; t < NT - 1; ++t) {
    asm volatile("s_waitcnt vmcnt(4)" ::: "memory");  // tile t landed (tile t+1 may be in flight)
    __builtin_amdgcn_s_barrier();
    if (t + 2 < NT) {
      int sb = cur + 2; if (sb >= 3) sb -= 3;
      stage(sb, (t + 2) * 32);
    }
    compute(cur);
    cur = (cur == 2) ? 0 : cur + 1;
  }
  asm volatile("s_waitcnt vmcnt(0)" ::: "memory");    // last tile: drain fully
  __builtin_amdgcn_s_barrier();
  compute(cur);

#pragma unroll
  for (int j = 0; j < 4; j++) {
    int col = n0 + wn + j * 16 + lm;
    float bc = bias[col];
    bool isV = col >= QD;            // uniform across lanes (64-aligned boundary)
    int c2 = isV ? col - QD : col;
    int h = c2 >> 6, d = c2 & 63;
#pragma unroll
    for (int i = 0; i < 4; i++) {
      int rowb = m0 + wm + i * 16 + q * 4;
#pragma unroll
      for (int r = 0; r < 4; r++) {
        int row = rowb + r;
        int b = row >> 11, m = row & 2047;
        float v = acc[i][j][r] + bc;
        if (isV)
          Vt[((((size_t)b * NHEAD + h) * HD) + d) * MM + m] = f2b(v);
        else
          Kh[(((size_t)b * NHEAD + h) * MM + m) * HD + d] = f2b(v);
      }
    }
  }
}

// ---------------- 64x64 bf16 MFMA GEMM for FFN (depth-2 pipelined, 3 buffers) ----------------
template <bool RELU, bool OUTF32>
__global__ __launch_bounds__(256) void k_gemm64(
    const uint16_t* __restrict__ A, const uint16_t* __restrict__ Bt,
    const float* __restrict__ bias, void* __restrict__ Cv, int K, int N) {
  __shared__ __align__(16) uint16_t As[3 * 2048];
  __shared__ __align__(16) uint16_t Bs[3 * 2048];
  int tid = threadIdx.x;
  int w = tid >> 6, l = tid & 63;
  int m0 = blockIdx.y * 64, n0 = blockIdx.x * 64;
  int wm = (w >> 1) * 32, wn = (w & 1) * 32;
  f32x4 zero4 = {0.f, 0.f, 0.f, 0.f};
  f32x4 acc[2][2];
#pragma unroll
  for (int i = 0; i < 2; i++)
#pragma unroll
    for (int j = 0; j < 2; j++) acc[i][j] = zero4;

  int sr = tid >> 2, sc = (tid & 3) * 8;
  const uint16_t* gA = A + (size_t)(m0 + sr) * K + sc;
  const uint16_t* gB = Bt + (size_t)(n0 + sr) * K + sc;
  int lm = l & 15, q = l >> 4;

  auto stage = [&](int buf, int kt) {
    glds16(gA + kt, As + buf * 2048 + w * 512);
    glds16(gB + kt, Bs + buf * 2048 + w * 512);
  };
  auto compute = [&](int buf) {
    const uint16_t* as = As + buf * 2048;
    const uint16_t* bs = Bs + buf * 2048;
    bf16x8 af[2], bfv[2];
#pragma unroll
    for (int i = 0; i < 2; i++) {
      af[i] = *(const bf16x8*)&as[(wm + i * 16 + lm) * 32 + q * 8];
      bfv[i] = *(const bf16x8*)&bs[(wn + i * 16 + lm) * 32 + q * 8];
    }
#pragma unroll
    for (int i = 0; i < 2; i++)
#pragma unroll
      for (int j = 0; j < 2; j++)
        acc[i][j] = __builtin_amdgcn_mfma_f32_16x16x32_bf16(af[i], bfv[j], acc[i][j], 0, 0, 0);
  };

  const int NT = K / 32;
  stage(0, 0);
  stage(1, 32);
  int cur = 0;
  for (int t = 0; t < NT - 1; ++t) {
    asm volatile("s_waitcnt vmcnt(2)" ::: "memory");
    __builtin_amdgcn_s_barrier();
    if (t + 2 < NT) {
      int sb = cur + 2; if (sb >= 3) sb -= 3;
      stage(sb, (t + 2) * 32);
    }
    compute(cur);
    cur = (cur == 2) ? 0 : cur + 1;
  }
  asm volatile("s_waitcnt vmcnt(0)" ::: "memory");
  __builtin_amdgcn_s_barrier();
  compute(cur);

#pragma unroll
  for (int j = 0; j < 2; j++) {
    int col = n0 + wn + j * 16 + lm;
    float bc = bias[col];
#pragma unroll
    for (int i = 0; i < 2; i++) {
      int rowb = m0 + wm + i * 16 + q * 4;
#pragma unroll
      for (int r = 0; r < 4; r++) {
        float v = acc[i][j][r] + bc;
        if (RELU) v = fmaxf(v, 0.f);
        if (OUTF32)
          ((float*)Cv)[(size_t)(rowb + r) * N + col] = v;
        else
          ((uint16_t*)Cv)[(size_t)(rowb + r) * N + col] = f2b(v);
      }
    }
  }
}

// ---------------- grouped Q projection ----------------
__global__ __launch_bounds__(256) void k_gemm_q(
    const uint16_t* __restrict__ Xb, const uint16_t* __restrict__ WQt,
    const float* __restrict__ bQ, float* __restrict__ Q) {
  __shared__ __align__(16) uint16_t As[32 * 32];
  __shared__ __align__(16) uint16_t Bs[64 * 32];
  int tid = threadIdx.x;
  int w = tid >> 6, l = tid & 63;
  int t = blockIdx.y, n0 = blockIdx.x * 64;
  const uint16_t* Wt = WQt + (size_t)t * QD * QD;
  f32x4 zero4 = {0.f, 0.f, 0.f, 0.f};
  f32x4 acc[2] = {zero4, zero4};
  int sr = tid >> 2, sc = (tid & 3) * 8;
  const uint16_t* gA = Xb + ((size_t)(sr * TT + t)) * QD + sc;
  const uint16_t* gB = Wt + (size_t)(n0 + sr) * QD + sc;
  int lm = l & 15, q = l >> 4;
  for (int kt = 0; kt < QD; kt += 32) {
    __syncthreads();
    if (tid < 128) glds16(gA + kt, As + w * 512);
    glds16(gB + kt, Bs + w * 512);
    __syncthreads();
    bf16x8 bfv = *(const bf16x8*)&Bs[(w * 16 + lm) * 32 + q * 8];
#pragma unroll
    for (int i = 0; i < 2; i++) {
      bf16x8 af = *(const bf16x8*)&As[(i * 16 + lm) * 32 + q * 8];
      acc[i] = __builtin_amdgcn_mfma_f32_16x16x32_bf16(af, bfv, acc[i], 0, 0, 0);
    }
  }
  int col = n0 + w * 16 + lm;
  float bc = bQ[t * QD + col];
#pragma unroll
  for (int i = 0; i < 2; i++) {
    int b0 = i * 16 + q * 4;
#pragma unroll
    for (int r = 0; r < 4; r++) {
      int b = b0 + r;
      Q[((size_t)(b * TT + t)) * QD + col] = acc[i][r] + bc;
    }
  }
}

// ---------------- scores + softmax -> attn_w ----------------
// grid (tg=2, h=12, b=32), block 256. K rows consumed whole (L1-friendly).
__global__ __launch_bounds__(256) void k_scores(
    const float* __restrict__ Q,      // [448][768]
    const uint16_t* __restrict__ Kh,  // [b][h][m][64]
    float* __restrict__ AW) {         // [B][T][H][M]
  __shared__ __align__(16) float Qs[7][64];
  __shared__ float redv[4];
  int tid = threadIdx.x;
  int tg = blockIdx.x, h = blockIdx.y, b = blockIdx.z;
  int t0 = tg * 7;
  for (int i = tid; i < 7 * 64; i += 256) {
    int t = i >> 6, d = i & 63;
    Qs[t][d] = Q[((size_t)(b * TT + t0 + t)) * QD + h * HD + d] * 0.125f;
  }
  __syncthreads();
  float acc[7][8];
#pragma unroll
  for (int t = 0; t < 7; t++)
#pragma unroll
    for (int c = 0; c < 8; c++) acc[t][c] = 0.f;

  const uint16_t* kb = Kh + ((size_t)(b * NHEAD + h)) * MM * HD;
  for (int c = 0; c < 8; c++) {
    const uint16_t* kr = kb + (size_t)(c * 256 + tid) * HD;
#pragma unroll
    for (int dv = 0; dv < 8; dv++) {
      uint4 u = *(const uint4*)(kr + dv * 8);
      float kf[8];
      kf[0] = __uint_as_float(u.x << 16); kf[1] = __uint_as_float(u.x & 0xffff0000u);
      kf[2] = __uint_as_float(u.y << 16); kf[3] = __uint_as_float(u.y & 0xffff0000u);
      kf[4] = __uint_as_float(u.z << 16); kf[5] = __uint_as_float(u.z & 0xffff0000u);
      kf[6] = __uint_as_float(u.w << 16); kf[7] = __uint_as_float(u.w & 0xffff0000u);
#pragma unroll
      for (int t = 0; t < 7; t++) {
        float4 qa = *(const float4*)&Qs[t][dv * 8];
        float4 qb = *(const float4*)&Qs[t][dv * 8 + 4];
        float s = acc[t][c];
        s = fmaf(kf[0], qa.x, s); s = fmaf(kf[1], qa.y, s);
        s = fmaf(kf[2], qa.z, s); s = fmaf(kf[3], qa.w, s);
        s = fmaf(kf[4], qb.x, s); s = fmaf(kf[5], qb.y, s);
        s = fmaf(kf[6], qb.z, s); s = fmaf(kf[7], qb.w, s);
        acc[t][c] = s;
      }
    }
  }
  // softmax per t over 2048
  int lane = tid & 63, w = tid >> 6;
#pragma unroll
  for (int t = 0; t < 7; t++) {
    float mx = acc[t][0];
#pragma unroll
    for (int c = 1; c < 8; c++) mx = fmaxf(mx, acc[t][c]);
#pragma unroll
    for (int o = 32; o > 0; o >>= 1) mx = fmaxf(mx, __shfl_xor(mx, o));
    if (lane == 0) redv[w] = mx;
    __syncthreads();
    mx = fmaxf(fmaxf(redv[0], redv[1]), fmaxf(redv[2], redv[3]));
    __syncthreads();
    float s = 0.f;
#pragma unroll
    for (int c = 0; c < 8; c++) {
      float e = __expf(acc[t][c] - mx);
      acc[t][c] = e;
      s += e;
    }
#pragma unroll
    for (int o = 32; o > 0; o >>= 1) s += __shfl_xor(s, o);
    if (lane == 0) redv[w] = s;
    __syncthreads();
    s = redv[0] + redv[1] + redv[2] + redv[3];
    __syncthreads();
    float inv = 1.f / s;
    size_t rowb = ((size_t)((b * TT + t0 + t) * NHEAD + h)) * MM;
#pragma unroll
    for (int c = 0; c < 8; c++) AW[rowb + c * 256 + tid] = acc[t][c] * inv;
  }
}

// ---------------- attn_out = attn_w @ V  (V pre-transposed per head) ----------------
// grid (12, 32), block 256. thread: d = tid&63 (own Vt row), wave tg -> t = tg*4+i.
__global__ __launch_bounds__(256) void k_attnout(
    const float* __restrict__ AW, const uint16_t* __restrict__ Vt,
    float* __restrict__ AO) {
  int tid = threadIdx.x;
  int h = blockIdx.x, b = blockIdx.y;
  int d = tid & 63, tg = tid >> 6;
  const uint16_t* vr = Vt + (((size_t)(b * NHEAD + h)) * HD + d) * MM;
  const float* pb = AW + ((size_t)(b * TT * NHEAD + h)) * MM;
  float acc[4] = {0.f, 0.f, 0.f, 0.f};
#pragma unroll 2
  for (int mc = 0; mc < MM; mc += 8) {
    uint4 u = *(const uint4*)(vr + mc);
    float vf[8];
    vf[0] = __uint_as_float(u.x << 16); vf[1] = __uint_as_float(u.x & 0xffff0000u);
    vf[2] = __uint_as_float(u.y << 16); vf[3] = __uint_as_float(u.y & 0xffff0000u);
    vf[4] = __uint_as_float(u.z << 16); vf[5] = __uint_as_float(u.z & 0xffff0000u);
    vf[6] = __uint_as_float(u.w << 16); vf[7] = __uint_as_float(u.w & 0xffff0000u);
#pragma unroll
    for (int i = 0; i < 4; i++) {
      int t = tg * 4 + i;
      if (t < TT) {
        const float* pr = pb + (size_t)t * NHEAD * MM + mc;
        float4 p0 = *(const float4*)pr;
        float4 p1 = *(const float4*)(pr + 4);
        float s = acc[i];
        s = fmaf(vf[0], p0.x, s); s = fmaf(vf[1], p0.y, s);
        s = fmaf(vf[2], p0.z, s); s = fmaf(vf[3], p0.w, s);
        s = fmaf(vf[4], p1.x, s); s = fmaf(vf[5], p1.y, s);
        s = fmaf(vf[6], p1.z, s); s = fmaf(vf[7], p1.w, s);
        acc[i] = s;
      }
    }
  }
#pragma unroll
  for (int i = 0; i < 4; i++) {
    int t = tg * 4 + i;
    if (t < TT) AO[((size_t)(b * TT + t)) * QD + h * HD + d] = acc[i];
  }
}

// ---------------- add + layernorm ----------------
__global__ __launch_bounds__(256) void k_add_ln(
    const float* __restrict__ X, const float* __restrict__ Y,
    const float* __restrict__ g, const float* __restrict__ be,
    float* __restrict__ outF, uint16_t* __restrict__ outB) {
  __shared__ float redS[4], redQ[4];
  int r = blockIdx.x, tid = threadIdx.x;
  size_t base = (size_t)r * QD;
  float e[3];
  float s = 0.f, sq = 0.f;
#pragma unroll
  for (int j = 0; j < 3; j++) {
    float v = X[base + tid + j * 256] + Y[base + tid + j * 256];
    e[j] = v; s += v; sq += v * v;
  }
#pragma unroll
  for (int o = 32; o > 0; o >>= 1) { s += __shfl_xor(s, o); sq += __shfl_xor(sq, o); }
  if ((tid & 63) == 0) { redS[tid >> 6] = s; redQ[tid >> 6] = sq; }
  __syncthreads();
  s = redS[0] + redS[1] + redS[2] + redS[3];
  sq = redQ[0] + redQ[1] + redQ[2] + redQ[3];
  float mu = s * (1.f / QD);
  float var = sq * (1.f / QD) - mu * mu;
  float rstd = rsqrtf(var + 1e-5f);
#pragma unroll
  for (int j = 0; j < 3; j++) {
    int i = tid + j * 256;
    float v = (e[j] - mu) * rstd * g[i] + be[i];
    outF[base + i] = v;
    if (outB) outB[base + i] = f2b(v);
  }
}

extern "C" void kernel_launch(void* const* d_in, const int* in_sizes, int n_in,
                              void* d_out, int out_size, void* d_ws, size_t ws_size,
                              hipStream_t stream) {
  const float* tok = (const float*)d_in[0];
  const float* kve = (const float*)d_in[1];
  const float* WQ  = (const float*)d_in[2];
  const float* bQ  = (const float*)d_in[3];
  const float* WK  = (const float*)d_in[4];
  const float* bK  = (const float*)d_in[5];
  const float* WV  = (const float*)d_in[6];
  const float* bV  = (const float*)d_in[7];
  const float* W1  = (const float*)d_in[8];
  const float* b1  = (const float*)d_in[9];
  const float* W2  = (const float*)d_in[10];
  const float* b2  = (const float*)d_in[11];
  const float* g1  = (const float*)d_in[12];
  const float* be1 = (const float*)d_in[13];
  const float* g2  = (const float*)d_in[14];
  const float* be2 = (const float*)d_in[15];

  float* outp = (float*)d_out;            // [448][768]
  float* AW = outp + 448 * 768;           // [32][14][12][2048]

  char* p = (char*)d_ws;
  auto nxt = [&](size_t bytes) -> char* {
    char* r = p;
    p += (bytes + 255) & ~(size_t)255;
    return r;
  };
  uint16_t* Abf   = (uint16_t*)nxt((size_t)67108864 * 2);   // KV embeddings bf16
  uint16_t* Kh    = (uint16_t*)nxt((size_t)50331648 * 2);   // [32][12][2048][64]
  uint16_t* Vt    = (uint16_t*)nxt((size_t)50331648 * 2);   // [32][12][64][2048]
  uint16_t* Wkvt  = (uint16_t*)nxt((size_t)1572864 * 2);    // [1536][1024]
  uint16_t* WQt   = (uint16_t*)nxt((size_t)8257536 * 2);    // [14][768][768]
  uint16_t* W1t   = (uint16_t*)nxt((size_t)2359296 * 2);    // [3072][768]
  uint16_t* W2t   = (uint16_t*)nxt((size_t)2359296 * 2);    // [768][3072]
  uint16_t* xtokb = (uint16_t*)nxt((size_t)344064 * 2);     // tokens bf16
  float* biaskv   = (float*)nxt(1536 * 4);
  float* Qws      = (float*)nxt((size_t)344064 * 4);
  float* AOws     = (float*)nxt((size_t)344064 * 4);
  float* xws      = (float*)nxt((size_t)344064 * 4);
  uint16_t* xbf   = (uint16_t*)nxt((size_t)344064 * 2);
  uint16_t* h1bf  = (uint16_t*)nxt((size_t)1376256 * 2);    // [448][3072]
  float* yws      = (float*)nxt((size_t)344064 * 4);

  // conversions
  k_cast8<<<dim3(32768), dim3(256), 0, stream>>>((const float4*)kve, (uint4*)Abf);
  k_cast8<<<dim3(168), dim3(256), 0, stream>>>((const float4*)tok, (uint4*)xtokb);
  k_transpose_bf16<<<dim3(24, 32, 1), dim3(256), 0, stream>>>(WK, Wkvt, 1024, 768);
  k_transpose_bf16<<<dim3(24, 32, 1), dim3(256), 0, stream>>>(WV, Wkvt + (size_t)768 * 1024, 1024, 768);
  k_transpose_bf16<<<dim3(24, 24, 14), dim3(256), 0, stream>>>(WQ, WQt, 768, 768);
  k_transpose_bf16<<<dim3(96, 24, 1), dim3(256), 0, stream>>>(W1, W1t, 768, 3072);
  k_transpose_bf16<<<dim3(24, 96, 1), dim3(256), 0, stream>>>(W2, W2t, 3072, 768);
  k_bias_concat<<<dim3(6), dim3(256), 0, stream>>>(bK, bV, biaskv);

  // K|V projection -> head-major K, transposed V
  k_gemm_kv<<<dim3(12, 512), dim3(256), 0, stream>>>(Abf, Wkvt, biaskv, Kh, Vt);

  // Q projection (per-t grouped)
  k_gemm_q<<<dim3(12, 14), dim3(256), 0, stream>>>(xtokb, WQt, bQ, Qws);

  // scores + softmax -> attn_w (f32, second output)
  k_scores<<<dim3(2, 12, 32), dim3(256), 0, stream>>>(Qws, Kh, AW);

  // attn_out = attn_w @ V
  k_attnout<<<dim3(12, 32), dim3(256), 0, stream>>>(AW, Vt, AOws);

  // x = LN(tok + attn_out)
  k_add_ln<<<dim3(448), dim3(256), 0, stream>>>(tok, AOws, g1, be1, xws, xbf);

  // FFN
  k_gemm64<true, false><<<dim3(48, 7), dim3(256), 0, stream>>>(xbf, W1t, b1, (void*)h1bf, 768, 3072);
  k_gemm64<false, true><<<dim3(12, 7), dim3(256), 0, stream>>>(h1bf, W2t, b2, (void*)yws, 3072, 768);

  // out = LN(x + ff)
  k_add_ln<<<dim3(448), dim3(256), 0, stream>>>(xws, yws, g2, be2, outp, (uint16_t*)nullptr);
}

// Round 3
// 1403.179 us; speedup vs baseline: 1.0090x; 1.0004x over previous
//
#include <hip/hip_runtime.h>
#include <cstdint>
#include <cstddef>

#define BBATCH 32
#define TT 14
#define MM 2048
#define QD 768
#define NHEAD 12
#define HD 64
#define FFD 3072
#define KVD 1024

typedef short bf16x8 __attribute__((ext_vector_type(8)));
typedef float f32x4 __attribute__((ext_vector_type(4)));

__device__ __forceinline__ uint16_t f2b(float f) {
  union { float f; uint32_t u; } v; v.f = f;
  uint32_t r = v.u + 0x7fffu + ((v.u >> 16) & 1u);
  return (uint16_t)(r >> 16);
}
__device__ __forceinline__ float b2f(uint16_t b) {
  union { uint32_t u; float f; } v; v.u = ((uint32_t)b) << 16; return v.f;
}

__device__ __forceinline__ void glds16(const void* g, void* l) {
  __builtin_amdgcn_global_load_lds(
      (const __attribute__((address_space(1))) void*)g,
      (__attribute__((address_space(3))) void*)l, 16, 0, 0);
}

// ---------------- cast f32 -> bf16, 8 elems/thread ----------------
__global__ void k_cast8(const float4* __restrict__ in, uint4* __restrict__ out) {
  int i = blockIdx.x * blockDim.x + threadIdx.x;
  float4 a = in[2 * i], b = in[2 * i + 1];
  uint4 o;
  o.x = (uint32_t)f2b(a.x) | ((uint32_t)f2b(a.y) << 16);
  o.y = (uint32_t)f2b(a.z) | ((uint32_t)f2b(a.w) << 16);
  o.z = (uint32_t)f2b(b.x) | ((uint32_t)f2b(b.y) << 16);
  o.w = (uint32_t)f2b(b.z) | ((uint32_t)f2b(b.w) << 16);
  out[i] = o;
}

// ------------- transpose-convert: in f32 [bz][R][C] -> out bf16 [bz][C][R] -------------
__global__ void k_transpose_bf16(const float* __restrict__ in, uint16_t* __restrict__ out,
                                 int R, int C) {
  __shared__ float tile[32][33];
  int bz = blockIdx.z;
  int c0 = blockIdx.x * 32, r0 = blockIdx.y * 32;
  int tx = threadIdx.x & 31, ty = threadIdx.x >> 5;  // 32 x 8
  const float* inb = in + (size_t)bz * R * C;
  uint16_t* outb = out + (size_t)bz * R * C;
#pragma unroll
  for (int rr = 0; rr < 32; rr += 8)
    tile[ty + rr][tx] = inb[(size_t)(r0 + ty + rr) * C + c0 + tx];
  __syncthreads();
#pragma unroll
  for (int rr = 0; rr < 32; rr += 8)
    outb[(size_t)(c0 + ty + rr) * R + r0 + tx] = f2b(tile[tx][ty + rr]);
}

__global__ void k_bias_concat(const float* __restrict__ bK, const float* __restrict__ bV,
                              float* __restrict__ out) {
  int i = blockIdx.x * 256 + threadIdx.x;  // 1536
  out[i] = (i < QD) ? bK[i] : bV[i - QD];
}

// ---------------- KV projection GEMM: 128x256 tiles ----------------
// A [65536][1024] bf16 (row = b*2048+m), Bt [1536][1024] bf16.
// K part (col<768):  Kh[b][h][m][64]   (h = col/64, d = col%64)
// V part (col>=768): Vt[b][h][d][2048] (h = (col-768)/64, d = (col-768)%64)
// 4 waves (2M x 2N), wave tile 64x128, acc[4][8]: each LDS frag read feeds 8 MFMAs.
// Depth-2 pipelined staging: 3 LDS buffers, counted vmcnt(6), one raw barrier per K-step.
// T2 slot-XOR swizzle (both-sides, rule #21): LDS stays linear (global_load_lds needs
// linear dest); global SOURCE slot is pre-XOR'd with (row>>1)&3; reads apply the same
// XOR. All row offsets (wm/wn/i*16/j*16/64-row stage strides) vanish mod 4 after >>1,
// so the read-side key is just kr=(lm>>1)&3. Spreads all 4 slots into each half-wave
// -> bank-conflict-free ds_read_b128.
__global__ __launch_bounds__(256, 2) void k_gemm_kv(
    const uint16_t* __restrict__ A, const uint16_t* __restrict__ Bt,
    const float* __restrict__ bias, uint16_t* __restrict__ Kh, uint16_t* __restrict__ Vt) {
  __shared__ __align__(16) uint16_t As[3 * 4096];   // 3 x [128][32]
  __shared__ __align__(16) uint16_t Bs[3 * 8192];   // 3 x [256][32]
  const int K = KVD;
  int tid = threadIdx.x;
  int w = tid >> 6, l = tid & 63;

  // XCD-aware bijective swizzle: nwg = 6*512 = 3072, 3072 % 8 == 0.
  // XCD k gets 384 contiguous swz ids = 64 contiguous M-panels x all 6 N-tiles.
  int wgid = blockIdx.y * 6 + blockIdx.x;
  int swz = (wgid & 7) * 384 + (wgid >> 3);
  int bx = swz % 6, by = swz / 6;
  int m0 = by * 128, n0 = bx * 256;
  int wm = (w >> 1) * 64, wn = (w & 1) * 128;

  f32x4 zero4 = {0.f, 0.f, 0.f, 0.f};
  f32x4 acc[4][8];
#pragma unroll
  for (int i = 0; i < 4; i++)
#pragma unroll
    for (int j = 0; j < 8; j++) acc[i][j] = zero4;

  int sr = tid >> 2;
  int xs8 = (((tid & 3) ^ ((tid >> 3) & 3))) * 8;   // pre-swizzled source slot
  const uint16_t* gA0 = A + (size_t)(m0 + sr) * K + xs8;
  const uint16_t* gA1 = A + (size_t)(m0 + 64 + sr) * K + xs8;
  const uint16_t* gB0 = Bt + (size_t)(n0 + sr) * K + xs8;
  const uint16_t* gB1 = Bt + (size_t)(n0 + 64 + sr) * K + xs8;
  const uint16_t* gB2 = Bt + (size_t)(n0 + 128 + sr) * K + xs8;
  const uint16_t* gB3 = Bt + (size_t)(n0 + 192 + sr) * K + xs8;

  int lm = l & 15, q = l >> 4;
  int qp = (q ^ ((lm >> 1) & 3)) * 8;               // swizzled read slot (elems)

  auto stage = [&](int buf, int kt) {
    uint16_t* a = As + buf * 4096 + w * 512;
    uint16_t* b = Bs + buf * 8192 + w * 512;
    glds16(gA0 + kt, a);
    glds16(gA1 + kt, a + 2048);
    glds16(gB0 + kt, b);
    glds16(gB1 + kt, b + 2048);
    glds16(gB2 + kt, b + 4096);
    glds16(gB3 + kt, b + 6144);
  };
  auto compute = [&](int buf) {
    const uint16_t* as = As + buf * 4096;
    const uint16_t* bs = Bs + buf * 8192;
    bf16x8 af[4], bfv[8];
#pragma unroll
    for (int i = 0; i < 4; i++)
      af[i] = *(const bf16x8*)&as[(wm + i * 16 + lm) * 32 + qp];
#pragma unroll
    for (int j = 0; j < 8; j++)
      bfv[j] = *(const bf16x8*)&bs[(wn + j * 16 + lm) * 32 + qp];
#pragma unroll
    for (int i = 0; i < 4; i++)
#pragma unroll
      for (int j = 0; j < 8; j++)
        acc[i][j] = __builtin_amdgcn_mfma_f32_16x16x32_bf16(af[i], bfv[j], acc[i][j], 0, 0, 0);
  };

  const int NT = K / 32;  // 32
  stage(0, 0);
  stage(1, 32);
  int cur = 0;
  for (int t = 0; t < NT - 1; ++t) {
    asm volatile("s_waitcnt vmcnt(6)" ::: "memory");  // tile t landed (t+1 in flight)
    __builtin_amdgcn_s_barrier();
    if (t + 2 < NT) {
      int sb = cur + 2; if (sb >= 3) sb -= 3;
      stage(sb, (t + 2) * 32);
    }
    compute(cur);
    cur = (cur == 2) ? 0 : cur + 1;
  }
  asm volatile("s_waitcnt vmcnt(0)" ::: "memory");
  __builtin_amdgcn_s_barrier();
  compute(cur);

#pragma unroll
  for (int j = 0; j < 8; j++) {
    int col = n0 + wn + j * 16 + lm;
    float bc = bias[col];
    bool isV = col >= QD;            // uniform across lanes (16-block never crosses 64)
    int c2 = isV ? col - QD : col;
    int h = c2 >> 6, d = c2 & 63;
#pragma unroll
    for (int i = 0; i < 4; i++) {
      int rowb = m0 + wm + i * 16 + q * 4;
#pragma unroll
      for (int r = 0; r < 4; r++) {
        int row = rowb + r;
        int b = row >> 11, m = row & 2047;
        float v = acc[i][j][r] + bc;
        if (isV)
          Vt[((((size_t)b * NHEAD + h) * HD) + d) * MM + m] = f2b(v);
        else
          Kh[(((size_t)b * NHEAD + h) * MM + m) * HD + d] = f2b(v);
      }
    }
  }
}

// ---------------- 64x64 bf16 MFMA GEMM for FFN (depth-2, 3 buffers, slot swizzle) ------------
template <bool RELU, bool OUTF32>
__global__ __launch_bounds__(256) void k_gemm64(
    const uint16_t* __restrict__ A, const uint16_t* __restrict__ Bt,
    const float* __restrict__ bias, void* __restrict__ Cv, int K, int N) {
  __shared__ __align__(16) uint16_t As[3 * 2048];
  __shared__ __align__(16) uint16_t Bs[3 * 2048];
  int tid = threadIdx.x;
  int w = tid >> 6, l = tid & 63;
  int m0 = blockIdx.y * 64, n0 = blockIdx.x * 64;
  int wm = (w >> 1) * 32, wn = (w & 1) * 32;
  f32x4 zero4 = {0.f, 0.f, 0.f, 0.f};
  f32x4 acc[2][2];
#pragma unroll
  for (int i = 0; i < 2; i++)
#pragma unroll
    for (int j = 0; j < 2; j++) acc[i][j] = zero4;

  int sr = tid >> 2;
  int xs8 = (((tid & 3) ^ ((tid >> 3) & 3))) * 8;
  const uint16_t* gA = A + (size_t)(m0 + sr) * K + xs8;
  const uint16_t* gB = Bt + (size_t)(n0 + sr) * K + xs8;
  int lm = l & 15, q = l >> 4;
  int qp = (q ^ ((lm >> 1) & 3)) * 8;

  auto stage = [&](int buf, int kt) {
    glds16(gA + kt, As + buf * 2048 + w * 512);
    glds16(gB + kt, Bs + buf * 2048 + w * 512);
  };
  auto compute = [&](int buf) {
    const uint16_t* as = As + buf * 2048;
    const uint16_t* bs = Bs + buf * 2048;
    bf16x8 af[2], bfv[2];
#pragma unroll
    for (int i = 0; i < 2; i++) {
      af[i] = *(const bf16x8*)&as[(wm + i * 16 + lm) * 32 + qp];
      bfv[i] = *(const bf16x8*)&bs[(wn + i * 16 + lm) * 32 + qp];
    }
#pragma unroll
    for (int i = 0; i < 2; i++)
#pragma unroll
      for (int j = 0; j < 2; j++)
        acc[i][j] = __builtin_amdgcn_mfma_f32_16x16x32_bf16(af[i], bfv[j], acc[i][j], 0, 0, 0);
  };

  const int NT = K / 32;
  stage(0, 0);
  stage(1, 32);
  int cur = 0;
  for (int t = 0; t < NT - 1; ++t) {
    asm volatile("s_waitcnt vmcnt(2)" ::: "memory");
    __builtin_amdgcn_s_barrier();
    if (t + 2 < NT) {
      int sb = cur + 2; if (sb >= 3) sb -= 3;
      stage(sb, (t + 2) * 32);
    }
    compute(cur);
    cur = (cur == 2) ? 0 : cur + 1;
  }
  asm volatile("s_waitcnt vmcnt(0)" ::: "memory");
  __builtin_amdgcn_s_barrier();
  compute(cur);

#pragma unroll
  for (int j = 0; j < 2; j++) {
    int col = n0 + wn + j * 16 + lm;
    float bc = bias[col];
#pragma unroll
    for (int i = 0; i < 2; i++) {
      int rowb = m0 + wm + i * 16 + q * 4;
#pragma unroll
      for (int r = 0; r < 4; r++) {
        float v = acc[i][j][r] + bc;
        if (RELU) v = fmaxf(v, 0.f);
        if (OUTF32)
          ((float*)Cv)[(size_t)(rowb + r) * N + col] = v;
        else
          ((uint16_t*)Cv)[(size_t)(rowb + r) * N + col] = f2b(v);
      }
    }
  }
}

// ---------------- grouped Q projection (slot swizzle) ----------------
__global__ __launch_bounds__(256) void k_gemm_q(
    const uint16_t* __restrict__ Xb, const uint16_t* __restrict__ WQt,
    const float* __restrict__ bQ, float* __restrict__ Q) {
  __shared__ __align__(16) uint16_t As[32 * 32];
  __shared__ __align__(16) uint16_t Bs[64 * 32];
  int tid = threadIdx.x;
  int w = tid >> 6, l = tid & 63;
  int t = blockIdx.y, n0 = blockIdx.x * 64;
  const uint16_t* Wt = WQt + (size_t)t * QD * QD;
  f32x4 zero4 = {0.f, 0.f, 0.f, 0.f};
  f32x4 acc[2] = {zero4, zero4};
  int sr = tid >> 2;
  int xs8 = (((tid & 3) ^ ((tid >> 3) & 3))) * 8;
  const uint16_t* gA = Xb + ((size_t)(sr * TT + t)) * QD + xs8;
  const uint16_t* gB = Wt + (size_t)(n0 + sr) * QD + xs8;
  int lm = l & 15, q = l >> 4;
  int qp = (q ^ ((lm >> 1) & 3)) * 8;
  for (int kt = 0; kt < QD; kt += 32) {
    __syncthreads();
    if (tid < 128) glds16(gA + kt, As + w * 512);
    glds16(gB + kt, Bs + w * 512);
    __syncthreads();
    bf16x8 bfv = *(const bf16x8*)&Bs[(w * 16 + lm) * 32 + qp];
#pragma unroll
    for (int i = 0; i < 2; i++) {
      bf16x8 af = *(const bf16x8*)&As[(i * 16 + lm) * 32 + qp];
      acc[i] = __builtin_amdgcn_mfma_f32_16x16x32_bf16(af, bfv, acc[i], 0, 0, 0);
    }
  }
  int col = n0 + w * 16 + lm;
  float bc = bQ[t * QD + col];
#pragma unroll
  for (int i = 0; i < 2; i++) {
    int b0 = i * 16 + q * 4;
#pragma unroll
    for (int r = 0; r < 4; r++) {
      int b = b0 + r;
      Q[((size_t)(b * TT + t)) * QD + col] = acc[i][r] + bc;
    }
  }
}

// ---------------- scores + softmax -> attn_w ----------------
// grid (tg=2, h=12, b=32), block 256. K rows consumed whole (L1-friendly).
__global__ __launch_bounds__(256) void k_scores(
    const float* __restrict__ Q,      // [448][768]
    const uint16_t* __restrict__ Kh,  // [b][h][m][64]
    float* __restrict__ AW) {         // [B][T][H][M]
  __shared__ __align__(16) float Qs[7][64];
  __shared__ float redv[4];
  int tid = threadIdx.x;
  int tg = blockIdx.x, h = blockIdx.y, b = blockIdx.z;
  int t0 = tg * 7;
  for (int i = tid; i < 7 * 64; i += 256) {
    int t = i >> 6, d = i & 63;
    Qs[t][d] = Q[((size_t)(b * TT + t0 + t)) * QD + h * HD + d] * 0.125f;
  }
  __syncthreads();
  float acc[7][8];
#pragma unroll
  for (int t = 0; t < 7; t++)
#pragma unroll
    for (int c = 0; c < 8; c++) acc[t][c] = 0.f;

  const uint16_t* kb = Kh + ((size_t)(b * NHEAD + h)) * MM * HD;
  for (int c = 0; c < 8; c++) {
    const uint16_t* kr = kb + (size_t)(c * 256 + tid) * HD;
#pragma unroll
    for (int dv = 0; dv < 8; dv++) {
      uint4 u = *(const uint4*)(kr + dv * 8);
      float kf[8];
      kf[0] = __uint_as_float(u.x << 16); kf[1] = __uint_as_float(u.x & 0xffff0000u);
      kf[2] = __uint_as_float(u.y << 16); kf[3] = __uint_as_float(u.y & 0xffff0000u);
      kf[4] = __uint_as_float(u.z << 16); kf[5] = __uint_as_float(u.z & 0xffff0000u);
      kf[6] = __uint_as_float(u.w << 16); kf[7] = __uint_as_float(u.w & 0xffff0000u);
#pragma unroll
      for (int t = 0; t < 7; t++) {
        float4 qa = *(const float4*)&Qs[t][dv * 8];
        float4 qb = *(const float4*)&Qs[t][dv * 8 + 4];
        float s = acc[t][c];
        s = fmaf(kf[0], qa.x, s); s = fmaf(kf[1], qa.y, s);
        s = fmaf(kf[2], qa.z, s); s = fmaf(kf[3], qa.w, s);
        s = fmaf(kf[4], qb.x, s); s = fmaf(kf[5], qb.y, s);
        s = fmaf(kf[6], qb.z, s); s = fmaf(kf[7], qb.w, s);
        acc[t][c] = s;
      }
    }
  }
  // softmax per t over 2048
  int lane = tid & 63, w = tid >> 6;
#pragma unroll
  for (int t = 0; t < 7; t++) {
    float mx = acc[t][0];
#pragma unroll
    for (int c = 1; c < 8; c++) mx = fmaxf(mx, acc[t][c]);
#pragma unroll
    for (int o = 32; o > 0; o >>= 1) mx = fmaxf(mx, __shfl_xor(mx, o));
    if (lane == 0) redv[w] = mx;
    __syncthreads();
    mx = fmaxf(fmaxf(redv[0], redv[1]), fmaxf(redv[2], redv[3]));
    __syncthreads();
    float s = 0.f;
#pragma unroll
    for (int c = 0; c < 8; c++) {
      float e = __expf(acc[t][c] - mx);
      acc[t][c] = e;
      s += e;
    }
#pragma unroll
    for (int o = 32; o > 0; o >>= 1) s += __shfl_xor(s, o);
    if (lane == 0) redv[w] = s;
    __syncthreads();
    s = redv[0] + redv[1] + redv[2] + redv[3];
    __syncthreads();
    float inv = 1.f / s;
    size_t rowb = ((size_t)((b * TT + t0 + t) * NHEAD + h)) * MM;
#pragma unroll
    for (int c = 0; c < 8; c++) AW[rowb + c * 256 + tid] = acc[t][c] * inv;
  }
}

// ---------------- attn_out = attn_w @ V  (V pre-transposed per head) ----------------
// grid (12, 32), block 256. thread: d = tid&63 (own Vt row), wave tg -> t = tg*4+i.
__global__ __launch_bounds__(256) void k_attnout(
    const float* __restrict__ AW, const uint16_t* __restrict__ Vt,
    float* __restrict__ AO) {
  int tid = threadIdx.x;
  int h = blockIdx.x, b = blockIdx.y;
  int d = tid & 63, tg = tid >> 6;
  const uint16_t* vr = Vt + (((size_t)(b * NHEAD + h)) * HD + d) * MM;
  const float* pb = AW + ((size_t)(b * TT * NHEAD + h)) * MM;
  float acc[4] = {0.f, 0.f, 0.f, 0.f};
#pragma unroll 2
  for (int mc = 0; mc < MM; mc += 8) {
    uint4 u = *(const uint4*)(vr + mc);
    float vf[8];
    vf[0] = __uint_as_float(u.x << 16); vf[1] = __uint_as_float(u.x & 0xffff0000u);
    vf[2] = __uint_as_float(u.y << 16); vf[3] = __uint_as_float(u.y & 0xffff0000u);
    vf[4] = __uint_as_float(u.z << 16); vf[5] = __uint_as_float(u.z & 0xffff0000u);
    vf[6] = __uint_as_float(u.w << 16); vf[7] = __uint_as_float(u.w & 0xffff0000u);
#pragma unroll
    for (int i = 0; i < 4; i++) {
      int t = tg * 4 + i;
      if (t < TT) {
        const float* pr = pb + (size_t)t * NHEAD * MM + mc;
        float4 p0 = *(const float4*)pr;
        float4 p1 = *(const float4*)(pr + 4);
        float s = acc[i];
        s = fmaf(vf[0], p0.x, s); s = fmaf(vf[1], p0.y, s);
        s = fmaf(vf[2], p0.z, s); s = fmaf(vf[3], p0.w, s);
        s = fmaf(vf[4], p1.x, s); s = fmaf(vf[5], p1.y, s);
        s = fmaf(vf[6], p1.z, s); s = fmaf(vf[7], p1.w, s);
        acc[i] = s;
      }
    }
  }
#pragma unroll
  for (int i = 0; i < 4; i++) {
    int t = tg * 4 + i;
    if (t < TT) AO[((size_t)(b * TT + t)) * QD + h * HD + d] = acc[i];
  }
}

// ---------------- add + layernorm ----------------
__global__ __launch_bounds__(256) void k_add_ln(
    const float* __restrict__ X, const float* __restrict__ Y,
    const float* __restrict__ g, const float* __restrict__ be,
    float* __restrict__ outF, uint16_t* __restrict__ outB) {
  __shared__ float redS[4], redQ[4];
  int r = blockIdx.x, tid = threadIdx.x;
  size_t base = (size_t)r * QD;
  float e[3];
  float s = 0.f, sq = 0.f;
#pragma unroll
  for (int j = 0; j < 3; j++) {
    float v = X[base + tid + j * 256] + Y[base + tid + j * 256];
    e[j] = v; s += v; sq += v * v;
  }
#pragma unroll
  for (int o = 32; o > 0; o >>= 1) { s += __shfl_xor(s, o); sq += __shfl_xor(sq, o); }
  if ((tid & 63) == 0) { redS[tid >> 6] = s; redQ[tid >> 6] = sq; }
  __syncthreads();
  s = redS[0] + redS[1] + redS[2] + redS[3];
  sq = redQ[0] + redQ[1] + redQ[2] + redQ[3];
  float mu = s * (1.f / QD);
  float var = sq * (1.f / QD) - mu * mu;
  float rstd = rsqrtf(var + 1e-5f);
#pragma unroll
  for (int j = 0; j < 3; j++) {
    int i = tid + j * 256;
    float v = (e[j] - mu) * rstd * g[i] + be[i];
    outF[base + i] = v;
    if (outB) outB[base + i] = f2b(v);
  }
}

extern "C" void kernel_launch(void* const* d_in, const int* in_sizes, int n_in,
                              void* d_out, int out_size, void* d_ws, size_t ws_size,
                              hipStream_t stream) {
  const float* tok = (const float*)d_in[0];
  const float* kve = (const float*)d_in[1];
  const float* WQ  = (const float*)d_in[2];
  const float* bQ  = (const float*)d_in[3];
  const float* WK  = (const float*)d_in[4];
  const float* bK  = (const float*)d_in[5];
  const float* WV  = (const float*)d_in[6];
  const float* bV  = (const float*)d_in[7];
  const float* W1  = (const float*)d_in[8];
  const float* b1  = (const float*)d_in[9];
  const float* W2  = (const float*)d_in[10];
  const float* b2  = (const float*)d_in[11];
  const float* g1  = (const float*)d_in[12];
  const float* be1 = (const float*)d_in[13];
  const float* g2  = (const float*)d_in[14];
  const float* be2 = (const float*)d_in[15];

  float* outp = (float*)d_out;            // [448][768]
  float* AW = outp + 448 * 768;           // [32][14][12][2048]

  char* p = (char*)d_ws;
  auto nxt = [&](size_t bytes) -> char* {
    char* r = p;
    p += (bytes + 255) & ~(size_t)255;
    return r;
  };
  uint16_t* Abf   = (uint16_t*)nxt((size_t)67108864 * 2);   // KV embeddings bf16
  uint16_t* Kh    = (uint16_t*)nxt((size_t)50331648 * 2);   // [32][12][2048][64]
  uint16_t* Vt    = (uint16_t*)nxt((size_t)50331648 * 2);   // [32][12][64][2048]
  uint16_t* Wkvt  = (uint16_t*)nxt((size_t)1572864 * 2);    // [1536][1024]
  uint16_t* WQt   = (uint16_t*)nxt((size_t)8257536 * 2);    // [14][768][768]
  uint16_t* W1t   = (uint16_t*)nxt((size_t)2359296 * 2);    // [3072][768]
  uint16_t* W2t   = (uint16_t*)nxt((size_t)2359296 * 2);    // [768][3072]
  uint16_t* xtokb = (uint16_t*)nxt((size_t)344064 * 2);     // tokens bf16
  float* biaskv   = (float*)nxt(1536 * 4);
  float* Qws      = (float*)nxt((size_t)344064 * 4);
  float* AOws     = (float*)nxt((size_t)344064 * 4);
  float* xws      = (float*)nxt((size_t)344064 * 4);
  uint16_t* xbf   = (uint16_t*)nxt((size_t)344064 * 2);
  uint16_t* h1bf  = (uint16_t*)nxt((size_t)1376256 * 2);    // [448][3072]
  float* yws      = (float*)nxt((size_t)344064 * 4);

  // conversions
  k_cast8<<<dim3(32768), dim3(256), 0, stream>>>((const float4*)kve, (uint4*)Abf);
  k_cast8<<<dim3(168), dim3(256), 0, stream>>>((const float4*)tok, (uint4*)xtokb);
  k_transpose_bf16<<<dim3(24, 32, 1), dim3(256), 0, stream>>>(WK, Wkvt, 1024, 768);
  k_transpose_bf16<<<dim3(24, 32, 1), dim3(256), 0, stream>>>(WV, Wkvt + (size_t)768 * 1024, 1024, 768);
  k_transpose_bf16<<<dim3(24, 24, 14), dim3(256), 0, stream>>>(WQ, WQt, 768, 768);
  k_transpose_bf16<<<dim3(96, 24, 1), dim3(256), 0, stream>>>(W1, W1t, 768, 3072);
  k_transpose_bf16<<<dim3(24, 96, 1), dim3(256), 0, stream>>>(W2, W2t, 3072, 768);
  k_bias_concat<<<dim3(6), dim3(256), 0, stream>>>(bK, bV, biaskv);

  // K|V projection -> head-major K, transposed V  (128x256 tiles)
  k_gemm_kv<<<dim3(6, 512), dim3(256), 0, stream>>>(Abf, Wkvt, biaskv, Kh, Vt);

  // Q projection (per-t grouped)
  k_gemm_q<<<dim3(12, 14), dim3(256), 0, stream>>>(xtokb, WQt, bQ, Qws);

  // scores + softmax -> attn_w (f32, second output)
  k_scores<<<dim3(2, 12, 32), dim3(256), 0, stream>>>(Qws, Kh, AW);

  // attn_out = attn_w @ V
  k_attnout<<<dim3(12, 32), dim3(256), 0, stream>>>(AW, Vt, AOws);

  // x = LN(tok + attn_out)
  k_add_ln<<<dim3(448), dim3(256), 0, stream>>>(tok, AOws, g1, be1, xws, xbf);

  // FFN
  k_gemm64<true, false><<<dim3(48, 7), dim3(256), 0, stream>>>(xbf, W1t, b1, (void*)h1bf, 768, 3072);
  k_gemm64<false, true><<<dim3(12, 7), dim3(256), 0, stream>>>(h1bf, W2t, b2, (void*)yws, 3072, 768);

  // out = LN(x + ff)
  k_add_ln<<<dim3(448), dim3(256), 0, stream>>>(xws, yws, g2, be2, outp, (uint16_t*)nullptr);
}

// Round 4
// 1223.992 us; speedup vs baseline: 1.1567x; 1.1464x over previous
//
#include <hip/hip_runtime.h>
#include <cstdint>
#include <cstddef>

#define BBATCH 32
#define TT 14
#define MM 2048
#define QD 768
#define NHEAD 12
#define HD 64
#define FFD 3072
#define KVD 1024
#define ROWS 448          // B*T
#define CHSTRIDE 344064   // 448*768

typedef short bf16x8 __attribute__((ext_vector_type(8)));
typedef float f32x4 __attribute__((ext_vector_type(4)));

__device__ __forceinline__ uint16_t f2b(float f) {
  union { float f; uint32_t u; } v; v.f = f;
  uint32_t r = v.u + 0x7fffu + ((v.u >> 16) & 1u);
  return (uint16_t)(r >> 16);
}
__device__ __forceinline__ float b2f(uint16_t b) {
  union { uint32_t u; float f; } v; v.u = ((uint32_t)b) << 16; return v.f;
}

__device__ __forceinline__ void glds16(const void* g, void* l) {
  __builtin_amdgcn_global_load_lds(
      (const __attribute__((address_space(1))) void*)g,
      (__attribute__((address_space(3))) void*)l, 16, 0, 0);
}

// ---------------- cast f32 -> bf16, 8 elems/thread ----------------
__global__ void k_cast8(const float4* __restrict__ in, uint4* __restrict__ out) {
  int i = blockIdx.x * blockDim.x + threadIdx.x;
  float4 a = in[2 * i], b = in[2 * i + 1];
  uint4 o;
  o.x = (uint32_t)f2b(a.x) | ((uint32_t)f2b(a.y) << 16);
  o.y = (uint32_t)f2b(a.z) | ((uint32_t)f2b(a.w) << 16);
  o.z = (uint32_t)f2b(b.x) | ((uint32_t)f2b(b.y) << 16);
  o.w = (uint32_t)f2b(b.z) | ((uint32_t)f2b(b.w) << 16);
  out[i] = o;
}

// ------------- transpose-convert: in f32 [bz][R][C] -> out bf16 [bz][C][R] -------------
__global__ void k_transpose_bf16(const float* __restrict__ in, uint16_t* __restrict__ out,
                                 int R, int C) {
  __shared__ float tile[32][33];
  int bz = blockIdx.z;
  int c0 = blockIdx.x * 32, r0 = blockIdx.y * 32;
  int tx = threadIdx.x & 31, ty = threadIdx.x >> 5;  // 32 x 8
  const float* inb = in + (size_t)bz * R * C;
  uint16_t* outb = out + (size_t)bz * R * C;
#pragma unroll
  for (int rr = 0; rr < 32; rr += 8)
    tile[ty + rr][tx] = inb[(size_t)(r0 + ty + rr) * C + c0 + tx];
  __syncthreads();
#pragma unroll
  for (int rr = 0; rr < 32; rr += 8)
    outb[(size_t)(c0 + ty + rr) * R + r0 + tx] = f2b(tile[tx][ty + rr]);
}

__global__ void k_bias_concat(const float* __restrict__ bK, const float* __restrict__ bV,
                              float* __restrict__ out) {
  int i = blockIdx.x * 256 + threadIdx.x;  // 1536
  out[i] = (i < QD) ? bK[i] : bV[i - QD];
}

// ---------------- KV projection GEMM: 128x256 tiles ----------------
// (unchanged from round 3 — structure ceiling; 8-phase port is a future round)
__global__ __launch_bounds__(256, 2) void k_gemm_kv(
    const uint16_t* __restrict__ A, const uint16_t* __restrict__ Bt,
    const float* __restrict__ bias, uint16_t* __restrict__ Kh, uint16_t* __restrict__ Vt) {
  __shared__ __align__(16) uint16_t As[3 * 4096];   // 3 x [128][32]
  __shared__ __align__(16) uint16_t Bs[3 * 8192];   // 3 x [256][32]
  const int K = KVD;
  int tid = threadIdx.x;
  int w = tid >> 6, l = tid & 63;

  int wgid = blockIdx.y * 6 + blockIdx.x;
  int swz = (wgid & 7) * 384 + (wgid >> 3);
  int bx = swz % 6, by = swz / 6;
  int m0 = by * 128, n0 = bx * 256;
  int wm = (w >> 1) * 64, wn = (w & 1) * 128;

  f32x4 zero4 = {0.f, 0.f, 0.f, 0.f};
  f32x4 acc[4][8];
#pragma unroll
  for (int i = 0; i < 4; i++)
#pragma unroll
    for (int j = 0; j < 8; j++) acc[i][j] = zero4;

  int sr = tid >> 2;
  int xs8 = (((tid & 3) ^ ((tid >> 3) & 3))) * 8;   // pre-swizzled source slot
  const uint16_t* gA0 = A + (size_t)(m0 + sr) * K + xs8;
  const uint16_t* gA1 = A + (size_t)(m0 + 64 + sr) * K + xs8;
  const uint16_t* gB0 = Bt + (size_t)(n0 + sr) * K + xs8;
  const uint16_t* gB1 = Bt + (size_t)(n0 + 64 + sr) * K + xs8;
  const uint16_t* gB2 = Bt + (size_t)(n0 + 128 + sr) * K + xs8;
  const uint16_t* gB3 = Bt + (size_t)(n0 + 192 + sr) * K + xs8;

  int lm = l & 15, q = l >> 4;
  int qp = (q ^ ((lm >> 1) & 3)) * 8;               // swizzled read slot (elems)

  auto stage = [&](int buf, int kt) {
    uint16_t* a = As + buf * 4096 + w * 512;
    uint16_t* b = Bs + buf * 8192 + w * 512;
    glds16(gA0 + kt, a);
    glds16(gA1 + kt, a + 2048);
    glds16(gB0 + kt, b);
    glds16(gB1 + kt, b + 2048);
    glds16(gB2 + kt, b + 4096);
    glds16(gB3 + kt, b + 6144);
  };
  auto compute = [&](int buf) {
    const uint16_t* as = As + buf * 4096;
    const uint16_t* bs = Bs + buf * 8192;
    bf16x8 af[4], bfv[8];
#pragma unroll
    for (int i = 0; i < 4; i++)
      af[i] = *(const bf16x8*)&as[(wm + i * 16 + lm) * 32 + qp];
#pragma unroll
    for (int j = 0; j < 8; j++)
      bfv[j] = *(const bf16x8*)&bs[(wn + j * 16 + lm) * 32 + qp];
#pragma unroll
    for (int i = 0; i < 4; i++)
#pragma unroll
      for (int j = 0; j < 8; j++)
        acc[i][j] = __builtin_amdgcn_mfma_f32_16x16x32_bf16(af[i], bfv[j], acc[i][j], 0, 0, 0);
  };

  const int NT = K / 32;  // 32
  stage(0, 0);
  stage(1, 32);
  int cur = 0;
  for (int t = 0; t < NT - 1; ++t) {
    asm volatile("s_waitcnt vmcnt(6)" ::: "memory");  // tile t landed (t+1 in flight)
    __builtin_amdgcn_s_barrier();
    if (t + 2 < NT) {
      int sb = cur + 2; if (sb >= 3) sb -= 3;
      stage(sb, (t + 2) * 32);
    }
    compute(cur);
    cur = (cur == 2) ? 0 : cur + 1;
  }
  asm volatile("s_waitcnt vmcnt(0)" ::: "memory");
  __builtin_amdgcn_s_barrier();
  compute(cur);

#pragma unroll
  for (int j = 0; j < 8; j++) {
    int col = n0 + wn + j * 16 + lm;
    float bc = bias[col];
    bool isV = col >= QD;            // uniform across lanes (16-block never crosses 64)
    int c2 = isV ? col - QD : col;
    int h = c2 >> 6, d = c2 & 63;
#pragma unroll
    for (int i = 0; i < 4; i++) {
      int rowb = m0 + wm + i * 16 + q * 4;
#pragma unroll
      for (int r = 0; r < 4; r++) {
        int row = rowb + r;
        int b = row >> 11, m = row & 2047;
        float v = acc[i][j][r] + bc;
        if (isV)
          Vt[((((size_t)b * NHEAD + h) * HD) + d) * MM + m] = f2b(v);
        else
          Kh[(((size_t)b * NHEAD + h) * MM + m) * HD + d] = f2b(v);
      }
    }
  }
}

// ---------------- 64x64 bf16 MFMA GEMM for FFN (depth-2, 3 buffers, slot swizzle) ------------
template <bool RELU, bool OUTF32>
__global__ __launch_bounds__(256) void k_gemm64(
    const uint16_t* __restrict__ A, const uint16_t* __restrict__ Bt,
    const float* __restrict__ bias, void* __restrict__ Cv, int K, int N) {
  __shared__ __align__(16) uint16_t As[3 * 2048];
  __shared__ __align__(16) uint16_t Bs[3 * 2048];
  int tid = threadIdx.x;
  int w = tid >> 6, l = tid & 63;
  int m0 = blockIdx.y * 64, n0 = blockIdx.x * 64;
  int wm = (w >> 1) * 32, wn = (w & 1) * 32;
  f32x4 zero4 = {0.f, 0.f, 0.f, 0.f};
  f32x4 acc[2][2];
#pragma unroll
  for (int i = 0; i < 2; i++)
#pragma unroll
    for (int j = 0; j < 2; j++) acc[i][j] = zero4;

  int sr = tid >> 2;
  int xs8 = (((tid & 3) ^ ((tid >> 3) & 3))) * 8;
  const uint16_t* gA = A + (size_t)(m0 + sr) * K + xs8;
  const uint16_t* gB = Bt + (size_t)(n0 + sr) * K + xs8;
  int lm = l & 15, q = l >> 4;
  int qp = (q ^ ((lm >> 1) & 3)) * 8;

  auto stage = [&](int buf, int kt) {
    glds16(gA + kt, As + buf * 2048 + w * 512);
    glds16(gB + kt, Bs + buf * 2048 + w * 512);
  };
  auto compute = [&](int buf) {
    const uint16_t* as = As + buf * 2048;
    const uint16_t* bs = Bs + buf * 2048;
    bf16x8 af[2], bfv[2];
#pragma unroll
    for (int i = 0; i < 2; i++) {
      af[i] = *(const bf16x8*)&as[(wm + i * 16 + lm) * 32 + qp];
      bfv[i] = *(const bf16x8*)&bs[(wn + i * 16 + lm) * 32 + qp];
    }
#pragma unroll
    for (int i = 0; i < 2; i++)
#pragma unroll
      for (int j = 0; j < 2; j++)
        acc[i][j] = __builtin_amdgcn_mfma_f32_16x16x32_bf16(af[i], bfv[j], acc[i][j], 0, 0, 0);
  };

  const int NT = K / 32;
  stage(0, 0);
  stage(1, 32);
  int cur = 0;
  for (int t = 0; t < NT - 1; ++t) {
    asm volatile("s_waitcnt vmcnt(2)" ::: "memory");
    __builtin_amdgcn_s_barrier();
    if (t + 2 < NT) {
      int sb = cur + 2; if (sb >= 3) sb -= 3;
      stage(sb, (t + 2) * 32);
    }
    compute(cur);
    cur = (cur == 2) ? 0 : cur + 1;
  }
  asm volatile("s_waitcnt vmcnt(0)" ::: "memory");
  __builtin_amdgcn_s_barrier();
  compute(cur);

#pragma unroll
  for (int j = 0; j < 2; j++) {
    int col = n0 + wn + j * 16 + lm;
    float bc = bias[col];
#pragma unroll
    for (int i = 0; i < 2; i++) {
      int rowb = m0 + wm + i * 16 + q * 4;
#pragma unroll
      for (int r = 0; r < 4; r++) {
        float v = acc[i][j][r] + bc;
        if (RELU) v = fmaxf(v, 0.f);
        if (OUTF32)
          ((float*)Cv)[(size_t)(rowb + r) * N + col] = v;
        else
          ((uint16_t*)Cv)[(size_t)(rowb + r) * N + col] = f2b(v);
      }
    }
  }
}

// ---------------- grouped Q projection (slot swizzle) ----------------
__global__ __launch_bounds__(256) void k_gemm_q(
    const uint16_t* __restrict__ Xb, const uint16_t* __restrict__ WQt,
    const float* __restrict__ bQ, float* __restrict__ Q) {
  __shared__ __align__(16) uint16_t As[32 * 32];
  __shared__ __align__(16) uint16_t Bs[64 * 32];
  int tid = threadIdx.x;
  int w = tid >> 6, l = tid & 63;
  int t = blockIdx.y, n0 = blockIdx.x * 64;
  const uint16_t* Wt = WQt + (size_t)t * QD * QD;
  f32x4 zero4 = {0.f, 0.f, 0.f, 0.f};
  f32x4 acc[2] = {zero4, zero4};
  int sr = tid >> 2;
  int xs8 = (((tid & 3) ^ ((tid >> 3) & 3))) * 8;
  const uint16_t* gA = Xb + ((size_t)(sr * TT + t)) * QD + xs8;
  const uint16_t* gB = Wt + (size_t)(n0 + sr) * QD + xs8;
  int lm = l & 15, q = l >> 4;
  int qp = (q ^ ((lm >> 1) & 3)) * 8;
  for (int kt = 0; kt < QD; kt += 32) {
    __syncthreads();
    if (tid < 128) glds16(gA + kt, As + w * 512);
    glds16(gB + kt, Bs + w * 512);
    __syncthreads();
    bf16x8 bfv = *(const bf16x8*)&Bs[(w * 16 + lm) * 32 + qp];
#pragma unroll
    for (int i = 0; i < 2; i++) {
      bf16x8 af = *(const bf16x8*)&As[(i * 16 + lm) * 32 + qp];
      acc[i] = __builtin_amdgcn_mfma_f32_16x16x32_bf16(af, bfv, acc[i], 0, 0, 0);
    }
  }
  int col = n0 + w * 16 + lm;
  float bc = bQ[t * QD + col];
#pragma unroll
  for (int i = 0; i < 2; i++) {
    int b0 = i * 16 + q * 4;
#pragma unroll
    for (int r = 0; r < 4; r++) {
      int b = b0 + r;
      Q[((size_t)(b * TT + t)) * QD + col] = acc[i][r] + bc;
    }
  }
}

// ---------------- scores + softmax -> attn_w ----------------
// grid (tg=2, h=12, b=32), block 256. K rows consumed whole (L1-friendly).
__global__ __launch_bounds__(256) void k_scores(
    const float* __restrict__ Q,      // [448][768]
    const uint16_t* __restrict__ Kh,  // [b][h][m][64]
    float* __restrict__ AW) {         // [B][T][H][M]
  __shared__ __align__(16) float Qs[7][64];
  __shared__ float redv[4];
  int tid = threadIdx.x;
  int tg = blockIdx.x, h = blockIdx.y, b = blockIdx.z;
  int t0 = tg * 7;
  for (int i = tid; i < 7 * 64; i += 256) {
    int t = i >> 6, d = i & 63;
    Qs[t][d] = Q[((size_t)(b * TT + t0 + t)) * QD + h * HD + d] * 0.125f;
  }
  __syncthreads();
  float acc[7][8];
#pragma unroll
  for (int t = 0; t < 7; t++)
#pragma unroll
    for (int c = 0; c < 8; c++) acc[t][c] = 0.f;

  const uint16_t* kb = Kh + ((size_t)(b * NHEAD + h)) * MM * HD;
  for (int c = 0; c < 8; c++) {
    const uint16_t* kr = kb + (size_t)(c * 256 + tid) * HD;
#pragma unroll
    for (int dv = 0; dv < 8; dv++) {
      uint4 u = *(const uint4*)(kr + dv * 8);
      float kf[8];
      kf[0] = __uint_as_float(u.x << 16); kf[1] = __uint_as_float(u.x & 0xffff0000u);
      kf[2] = __uint_as_float(u.y << 16); kf[3] = __uint_as_float(u.y & 0xffff0000u);
      kf[4] = __uint_as_float(u.z << 16); kf[5] = __uint_as_float(u.z & 0xffff0000u);
      kf[6] = __uint_as_float(u.w << 16); kf[7] = __uint_as_float(u.w & 0xffff0000u);
#pragma unroll
      for (int t = 0; t < 7; t++) {
        float4 qa = *(const float4*)&Qs[t][dv * 8];
        float4 qb = *(const float4*)&Qs[t][dv * 8 + 4];
        float s = acc[t][c];
        s = fmaf(kf[0], qa.x, s); s = fmaf(kf[1], qa.y, s);
        s = fmaf(kf[2], qa.z, s); s = fmaf(kf[3], qa.w, s);
        s = fmaf(kf[4], qb.x, s); s = fmaf(kf[5], qb.y, s);
        s = fmaf(kf[6], qb.z, s); s = fmaf(kf[7], qb.w, s);
        acc[t][c] = s;
      }
    }
  }
  // softmax per t over 2048
  int lane = tid & 63, w = tid >> 6;
#pragma unroll
  for (int t = 0; t < 7; t++) {
    float mx = acc[t][0];
#pragma unroll
    for (int c = 1; c < 8; c++) mx = fmaxf(mx, acc[t][c]);
#pragma unroll
    for (int o = 32; o > 0; o >>= 1) mx = fmaxf(mx, __shfl_xor(mx, o));
    if (lane == 0) redv[w] = mx;
    __syncthreads();
    mx = fmaxf(fmaxf(redv[0], redv[1]), fmaxf(redv[2], redv[3]));
    __syncthreads();
    float s = 0.f;
#pragma unroll
    for (int c = 0; c < 8; c++) {
      float e = __expf(acc[t][c] - mx);
      acc[t][c] = e;
      s += e;
    }
#pragma unroll
    for (int o = 32; o > 0; o >>= 1) s += __shfl_xor(s, o);
    if (lane == 0) redv[w] = s;
    __syncthreads();
    s = redv[0] + redv[1] + redv[2] + redv[3];
    __syncthreads();
    float inv = 1.f / s;
    size_t rowb = ((size_t)((b * TT + t0 + t) * NHEAD + h)) * MM;
#pragma unroll
    for (int c = 0; c < 8; c++) AW[rowb + c * 256 + tid] = acc[t][c] * inv;
  }
}

// ---------------- partial attn_out = attn_w @ V over m-chunks ----------------
// grid (12, 32, 8), block 256. Same per-thread memory pattern as before (lane owns a
// Vt d-row, AW rows broadcast), but 8x the blocks (12/CU): latency now hidden by TLP.
// Partials pbuf[mc][b*TT+t][h*64+d] are reduced inside k_add_ln.
__global__ __launch_bounds__(256) void k_attnout(
    const float* __restrict__ AW, const uint16_t* __restrict__ Vt,
    float* __restrict__ pbuf) {
  int tid = threadIdx.x;
  int h = blockIdx.x, b = blockIdx.y, mc = blockIdx.z;
  int d = tid & 63, tg = tid >> 6;
  int m0 = mc * 256;
  const uint16_t* vr = Vt + (((size_t)(b * NHEAD + h)) * HD + d) * MM + m0;
  const float* pb = AW + ((size_t)(b * TT * NHEAD + h)) * MM + m0;
  float acc[4] = {0.f, 0.f, 0.f, 0.f};
#pragma unroll 2
  for (int mcc = 0; mcc < 256; mcc += 8) {
    uint4 u = *(const uint4*)(vr + mcc);
    float vf[8];
    vf[0] = __uint_as_float(u.x << 16); vf[1] = __uint_as_float(u.x & 0xffff0000u);
    vf[2] = __uint_as_float(u.y << 16); vf[3] = __uint_as_float(u.y & 0xffff0000u);
    vf[4] = __uint_as_float(u.z << 16); vf[5] = __uint_as_float(u.z & 0xffff0000u);
    vf[6] = __uint_as_float(u.w << 16); vf[7] = __uint_as_float(u.w & 0xffff0000u);
#pragma unroll
    for (int i = 0; i < 4; i++) {
      int t = tg * 4 + i;
      if (t < TT) {
        const float* pr = pb + (size_t)t * NHEAD * MM + mcc;
        float4 p0 = *(const float4*)pr;
        float4 p1 = *(const float4*)(pr + 4);
        float s = acc[i];
        s = fmaf(vf[0], p0.x, s); s = fmaf(vf[1], p0.y, s);
        s = fmaf(vf[2], p0.z, s); s = fmaf(vf[3], p0.w, s);
        s = fmaf(vf[4], p1.x, s); s = fmaf(vf[5], p1.y, s);
        s = fmaf(vf[6], p1.z, s); s = fmaf(vf[7], p1.w, s);
        acc[i] = s;
      }
    }
  }
#pragma unroll
  for (int i = 0; i < 4; i++) {
    int t = tg * 4 + i;
    if (t < TT)
      pbuf[(size_t)mc * CHSTRIDE + ((size_t)(b * TT + t)) * QD + h * HD + d] = acc[i];
  }
}

// ---------------- add + layernorm (with NCHUNK-way partial reduce of Y) ----------------
template <int NCHUNK>
__global__ __launch_bounds__(256) void k_add_ln(
    const float* __restrict__ X, const float* __restrict__ P,
    const float* __restrict__ g, const float* __restrict__ be,
    float* __restrict__ outF, uint16_t* __restrict__ outB) {
  __shared__ float redS[4], redQ[4];
  int r = blockIdx.x, tid = threadIdx.x;
  size_t base = (size_t)r * QD;
  float e[3];
  float s = 0.f, sq = 0.f;
#pragma unroll
  for (int j = 0; j < 3; j++) {
    int i = tid + j * 256;
    float v = X[base + i];
#pragma unroll
    for (int c = 0; c < NCHUNK; c++) v += P[(size_t)c * CHSTRIDE + base + i];
    e[j] = v; s += v; sq += v * v;
  }
#pragma unroll
  for (int o = 32; o > 0; o >>= 1) { s += __shfl_xor(s, o); sq += __shfl_xor(sq, o); }
  if ((tid & 63) == 0) { redS[tid >> 6] = s; redQ[tid >> 6] = sq; }
  __syncthreads();
  s = redS[0] + redS[1] + redS[2] + redS[3];
  sq = redQ[0] + redQ[1] + redQ[2] + redQ[3];
  float mu = s * (1.f / QD);
  float var = sq * (1.f / QD) - mu * mu;
  float rstd = rsqrtf(var + 1e-5f);
#pragma unroll
  for (int j = 0; j < 3; j++) {
    int i = tid + j * 256;
    float v = (e[j] - mu) * rstd * g[i] + be[i];
    outF[base + i] = v;
    if (outB) outB[base + i] = f2b(v);
  }
}

extern "C" void kernel_launch(void* const* d_in, const int* in_sizes, int n_in,
                              void* d_out, int out_size, void* d_ws, size_t ws_size,
                              hipStream_t stream) {
  const float* tok = (const float*)d_in[0];
  const float* kve = (const float*)d_in[1];
  const float* WQ  = (const float*)d_in[2];
  const float* bQ  = (const float*)d_in[3];
  const float* WK  = (const float*)d_in[4];
  const float* bK  = (const float*)d_in[5];
  const float* WV  = (const float*)d_in[6];
  const float* bV  = (const float*)d_in[7];
  const float* W1  = (const float*)d_in[8];
  const float* b1  = (const float*)d_in[9];
  const float* W2  = (const float*)d_in[10];
  const float* b2  = (const float*)d_in[11];
  const float* g1  = (const float*)d_in[12];
  const float* be1 = (const float*)d_in[13];
  const float* g2  = (const float*)d_in[14];
  const float* be2 = (const float*)d_in[15];

  float* outp = (float*)d_out;            // [448][768]
  float* AW = outp + 448 * 768;           // [32][14][12][2048]

  char* p = (char*)d_ws;
  auto nxt = [&](size_t bytes) -> char* {
    char* r = p;
    p += (bytes + 255) & ~(size_t)255;
    return r;
  };
  uint16_t* Abf   = (uint16_t*)nxt((size_t)67108864 * 2);   // KV embeddings bf16
  uint16_t* Kh    = (uint16_t*)nxt((size_t)50331648 * 2);   // [32][12][2048][64]
  uint16_t* Vt    = (uint16_t*)nxt((size_t)50331648 * 2);   // [32][12][64][2048]
  uint16_t* Wkvt  = (uint16_t*)nxt((size_t)1572864 * 2);    // [1536][1024]
  uint16_t* WQt   = (uint16_t*)nxt((size_t)8257536 * 2);    // [14][768][768]
  uint16_t* W1t   = (uint16_t*)nxt((size_t)2359296 * 2);    // [3072][768]
  uint16_t* W2t   = (uint16_t*)nxt((size_t)2359296 * 2);    // [768][3072]
  uint16_t* xtokb = (uint16_t*)nxt((size_t)344064 * 2);     // tokens bf16
  float* biaskv   = (float*)nxt(1536 * 4);
  float* Qws      = (float*)nxt((size_t)344064 * 4);
  float* pbuf     = (float*)nxt((size_t)8 * CHSTRIDE * 4);  // attn_out partials
  float* xws      = (float*)nxt((size_t)344064 * 4);
  uint16_t* xbf   = (uint16_t*)nxt((size_t)344064 * 2);
  uint16_t* h1bf  = (uint16_t*)nxt((size_t)1376256 * 2);    // [448][3072]
  float* yws      = (float*)nxt((size_t)344064 * 4);

  // conversions
  k_cast8<<<dim3(32768), dim3(256), 0, stream>>>((const float4*)kve, (uint4*)Abf);
  k_cast8<<<dim3(168), dim3(256), 0, stream>>>((const float4*)tok, (uint4*)xtokb);
  k_transpose_bf16<<<dim3(24, 32, 1), dim3(256), 0, stream>>>(WK, Wkvt, 1024, 768);
  k_transpose_bf16<<<dim3(24, 32, 1), dim3(256), 0, stream>>>(WV, Wkvt + (size_t)768 * 1024, 1024, 768);
  k_transpose_bf16<<<dim3(24, 24, 14), dim3(256), 0, stream>>>(WQ, WQt, 768, 768);
  k_transpose_bf16<<<dim3(96, 24, 1), dim3(256), 0, stream>>>(W1, W1t, 768, 3072);
  k_transpose_bf16<<<dim3(24, 96, 1), dim3(256), 0, stream>>>(W2, W2t, 3072, 768);
  k_bias_concat<<<dim3(6), dim3(256), 0, stream>>>(bK, bV, biaskv);

  // K|V projection -> head-major K, transposed V  (128x256 tiles)
  k_gemm_kv<<<dim3(6, 512), dim3(256), 0, stream>>>(Abf, Wkvt, biaskv, Kh, Vt);

  // Q projection (per-t grouped)
  k_gemm_q<<<dim3(12, 14), dim3(256), 0, stream>>>(xtokb, WQt, bQ, Qws);

  // scores + softmax -> attn_w (f32, second output)
  k_scores<<<dim3(2, 12, 32), dim3(256), 0, stream>>>(Qws, Kh, AW);

  // attn_out partials over 8 m-chunks (latency-hiding via 3072 blocks)
  k_attnout<<<dim3(12, 32, 8), dim3(256), 0, stream>>>(AW, Vt, pbuf);

  // x = LN(tok + sum_mc pbuf[mc])
  k_add_ln<8><<<dim3(448), dim3(256), 0, stream>>>(tok, pbuf, g1, be1, xws, xbf);

  // FFN
  k_gemm64<true, false><<<dim3(48, 7), dim3(256), 0, stream>>>(xbf, W1t, b1, (void*)h1bf, 768, 3072);
  k_gemm64<false, true><<<dim3(12, 7), dim3(256), 0, stream>>>(h1bf, W2t, b2, (void*)yws, 3072, 768);

  // out = LN(x + ff)
  k_add_ln<1><<<dim3(448), dim3(256), 0, stream>>>(xws, yws, g2, be2, outp, (uint16_t*)nullptr);
}

// Round 5
// 1219.414 us; speedup vs baseline: 1.1611x; 1.0038x over previous
//
#include <hip/hip_runtime.h>
#include <cstdint>
#include <cstddef>

#define BBATCH 32
#define TT 14
#define MM 2048
#define QD 768
#define NHEAD 12
#define HD 64
#define FFD 3072
#define KVD 1024
#define ROWS 448          // B*T
#define CHSTRIDE 344064   // 448*768

typedef short bf16x8 __attribute__((ext_vector_type(8)));
typedef float f32x4 __attribute__((ext_vector_type(4)));

__device__ __forceinline__ uint16_t f2b(float f) {
  union { float f; uint32_t u; } v; v.f = f;
  uint32_t r = v.u + 0x7fffu + ((v.u >> 16) & 1u);
  return (uint16_t)(r >> 16);
}
__device__ __forceinline__ float b2f(uint16_t b) {
  union { uint32_t u; float f; } v; v.u = ((uint32_t)b) << 16; return v.f;
}

__device__ __forceinline__ void glds16(const void* g, void* l) {
  __builtin_amdgcn_global_load_lds(
      (const __attribute__((address_space(1))) void*)g,
      (__attribute__((address_space(3))) void*)l, 16, 0, 0);
}

#define BARM asm volatile("s_barrier" ::: "memory")

// ---------------- cast f32 -> bf16, 8 elems/thread ----------------
__global__ void k_cast8(const float4* __restrict__ in, uint4* __restrict__ out) {
  int i = blockIdx.x * blockDim.x + threadIdx.x;
  float4 a = in[2 * i], b = in[2 * i + 1];
  uint4 o;
  o.x = (uint32_t)f2b(a.x) | ((uint32_t)f2b(a.y) << 16);
  o.y = (uint32_t)f2b(a.z) | ((uint32_t)f2b(a.w) << 16);
  o.z = (uint32_t)f2b(b.x) | ((uint32_t)f2b(b.y) << 16);
  o.w = (uint32_t)f2b(b.z) | ((uint32_t)f2b(b.w) << 16);
  out[i] = o;
}

// ------------- transpose-convert: in f32 [bz][R][C] -> out bf16 [bz][C][R] -------------
__global__ void k_transpose_bf16(const float* __restrict__ in, uint16_t* __restrict__ out,
                                 int R, int C) {
  __shared__ float tile[32][33];
  int bz = blockIdx.z;
  int c0 = blockIdx.x * 32, r0 = blockIdx.y * 32;
  int tx = threadIdx.x & 31, ty = threadIdx.x >> 5;  // 32 x 8
  const float* inb = in + (size_t)bz * R * C;
  uint16_t* outb = out + (size_t)bz * R * C;
#pragma unroll
  for (int rr = 0; rr < 32; rr += 8)
    tile[ty + rr][tx] = inb[(size_t)(r0 + ty + rr) * C + c0 + tx];
  __syncthreads();
#pragma unroll
  for (int rr = 0; rr < 32; rr += 8)
    outb[(size_t)(c0 + ty + rr) * R + r0 + tx] = f2b(tile[tx][ty + rr]);
}

__global__ void k_bias_concat(const float* __restrict__ bK, const float* __restrict__ bV,
                              float* __restrict__ out) {
  int i = blockIdx.x * 256 + threadIdx.x;  // 1536
  out[i] = (i < QD) ? bK[i] : bV[i - QD];
}

// ---------------- KV projection GEMM: 256x256 tile, 8-phase schedule ----------------
// A [65536][1024] bf16 (row = b*2048+m), Bt [1536][1024] bf16.
// 8 waves (2M x 4N), wave tile 128x64, acc[8][4]. BK=64, NT=16 K-tiles.
// LDS: 2 K-tile double buffer, A[256][64]+B[256][64] bf16 per tile = 128 KiB.
// Swizzle (rule #21, both-sides): LDS dest linear (global_load_lds), global SOURCE
// chunk pre-XOR'd with row&7, read chunk = (s*4+q)^(lm&7). Gives the structural
// 8-cycle minimum per ds_read_b128 (linear layout would be 16-way).
// Schedule per K-tile t, phases P0..P3 = (k0,Mlo)(k0,Mhi)(k1,Mlo)(k1,Mhi); B frags
// read at P0/P2, reused at P1/P3. Staging one half-tile per phase, 1.25 tiles ahead:
//   B1(t+1)@P0, A0(t+1)@P1, A1(t+1)@P2  -> dead buffer (tile t-1's regions)
//   B0(t+2)@P3 -> current buffer's B0, last read at P2 (P2->P3 barrier orders it)
// Boundary: vmcnt(2) at P3 confirms tile t+1 (leaves B0(t+2) in flight); vmcnt(0)
// at t=NT-2; barriers are asm s_barrier+memory-clobber (compile-time fence, no drain).
__global__ __launch_bounds__(512, 2) void k_gemm_kv(
    const uint16_t* __restrict__ A, const uint16_t* __restrict__ Bt,
    const float* __restrict__ bias, uint16_t* __restrict__ Kh, uint16_t* __restrict__ Vt) {
  __shared__ __align__(16) uint16_t As[2 * 16384];
  __shared__ __align__(16) uint16_t Bs[2 * 16384];
  const int K = KVD;
  int tid = threadIdx.x;
  int w = tid >> 6, l = tid & 63;
  int wr = w >> 2, wc = w & 3;

  // XCD swizzle: nwg = 6*256 = 1536, 1536 % 8 == 0 -> bijective.
  int wgid = blockIdx.y * 6 + blockIdx.x;
  int swz = (wgid & 7) * 192 + (wgid >> 3);
  int bx = swz % 6, by = swz / 6;
  int m0 = by * 256, n0 = bx * 256;

  f32x4 zero4 = {0.f, 0.f, 0.f, 0.f};
  f32x4 acc[8][4];
#pragma unroll
  for (int i = 0; i < 8; i++)
#pragma unroll
    for (int j = 0; j < 4; j++) acc[i][j] = zero4;

  // staging: 512 threads cover 64 rows x 8 chunks per 8KB round; 2 rounds/half-tile
  int srow = tid >> 3;
  int schk8 = ((tid & 7) ^ (srow & 7)) * 8;   // pre-swizzled source chunk (elems)
  const uint16_t* gA = A + (size_t)(m0 + srow) * K + schk8;
  const uint16_t* gB = Bt + (size_t)(n0 + srow) * K + schk8;
  int ldsW = w * 512;                          // wave-uniform LDS base (elems)

  auto stA = [&](int b, int T, int half) {
    uint16_t* d = As + b * 16384 + half * 8192 + ldsW;
    const uint16_t* s = gA + (size_t)(half * 128) * K + T * 64;
    glds16(s, d);
    glds16(s + (size_t)64 * K, d + 4096);
  };
  auto stB = [&](int b, int T, int half) {
    uint16_t* d = Bs + b * 16384 + half * 8192 + ldsW;
    const uint16_t* s = gB + (size_t)(half * 128) * K + T * 64;
    glds16(s, d);
    glds16(s + (size_t)64 * K, d + 4096);
  };

  int lm = l & 15, q = l >> 4;
  int xk = lm & 7;
  auto LDA = [&](int b, int row, int s) -> bf16x8 {
    return *(const bf16x8*)&As[b * 16384 + row * 64 + (((s << 2) + q) ^ xk) * 8];
  };
  auto LDB = [&](int b, int row, int s) -> bf16x8 {
    return *(const bf16x8*)&Bs[b * 16384 + row * 64 + (((s << 2) + q) ^ xk) * 8];
  };

  const int NT = K / 64;  // 16
  // prologue: full tile 0 + B0(1); vmcnt(2) leaves only B0(1) in flight
  stB(0, 0, 0); stB(0, 0, 1); stA(0, 0, 0); stA(0, 0, 1);
  stB(1, 1, 0);
  asm volatile("s_waitcnt vmcnt(2)" ::: "memory");
  BARM;

  int arow = wr * 128 + lm;
  int brow = wc * 64 + lm;

  for (int t = 0; t < NT; ++t) {
    int cur = t & 1, nxt = cur ^ 1;
    bf16x8 a0[4], b0[4], b1[4];
    // ---- P0: (k0, Mlo) + B frags k0 ----
#pragma unroll
    for (int i = 0; i < 4; i++) a0[i] = LDA(cur, arow + i * 16, 0);
#pragma unroll
    for (int j = 0; j < 4; j++) b0[j] = LDB(cur, brow + j * 16, 0);
    if (t + 1 < NT) stB(nxt, t + 1, 1);
    BARM;
    __builtin_amdgcn_s_setprio(1);
#pragma unroll
    for (int i = 0; i < 4; i++)
#pragma unroll
      for (int j = 0; j < 4; j++)
        acc[i][j] = __builtin_amdgcn_mfma_f32_16x16x32_bf16(a0[i], b0[j], acc[i][j], 0, 0, 0);
    __builtin_amdgcn_s_setprio(0);
    BARM;
    // ---- P1: (k0, Mhi), reuse b0 ----
#pragma unroll
    for (int i = 0; i < 4; i++) a0[i] = LDA(cur, arow + 64 + i * 16, 0);
    if (t + 1 < NT) stA(nxt, t + 1, 0);
    BARM;
    __builtin_amdgcn_s_setprio(1);
#pragma unroll
    for (int i = 0; i < 4; i++)
#pragma unroll
      for (int j = 0; j < 4; j++)
        acc[4 + i][j] = __builtin_amdgcn_mfma_f32_16x16x32_bf16(a0[i], b0[j], acc[4 + i][j], 0, 0, 0);
    __builtin_amdgcn_s_setprio(0);
    BARM;
    // ---- P2: (k1, Mlo) + B frags k1 ----
#pragma unroll
    for (int i = 0; i < 4; i++) a0[i] = LDA(cur, arow + i * 16, 1);
#pragma unroll
    for (int j = 0; j < 4; j++) b1[j] = LDB(cur, brow + j * 16, 1);
    if (t + 1 < NT) stA(nxt, t + 1, 1);
    BARM;
    __builtin_amdgcn_s_setprio(1);
#pragma unroll
    for (int i = 0; i < 4; i++)
#pragma unroll
      for (int j = 0; j < 4; j++)
        acc[i][j] = __builtin_amdgcn_mfma_f32_16x16x32_bf16(a0[i], b1[j], acc[i][j], 0, 0, 0);
    __builtin_amdgcn_s_setprio(0);
    BARM;
    // ---- P3: (k1, Mhi), reuse b1; stage B0(t+2) into current buffer ----
#pragma unroll
    for (int i = 0; i < 4; i++) a0[i] = LDA(cur, arow + 64 + i * 16, 1);
    if (t + 2 < NT) stB(cur, t + 2, 0);
    BARM;
    __builtin_amdgcn_s_setprio(1);
#pragma unroll
    for (int i = 0; i < 4; i++)
#pragma unroll
      for (int j = 0; j < 4; j++)
        acc[4 + i][j] = __builtin_amdgcn_mfma_f32_16x16x32_bf16(a0[i], b1[j], acc[4 + i][j], 0, 0, 0);
    __builtin_amdgcn_s_setprio(0);
    if (t + 2 < NT)
      asm volatile("s_waitcnt vmcnt(2)" ::: "memory");
    else if (t + 1 < NT)
      asm volatile("s_waitcnt vmcnt(0)" ::: "memory");
    BARM;
  }

#pragma unroll
  for (int j = 0; j < 4; j++) {
    int col = n0 + wc * 64 + j * 16 + lm;
    float bc = bias[col];
    bool isV = col >= QD;            // uniform across lanes (16-block never crosses 64)
    int c2 = isV ? col - QD : col;
    int h = c2 >> 6, d = c2 & 63;
#pragma unroll
    for (int i = 0; i < 8; i++) {
      int rowb = m0 + wr * 128 + i * 16 + q * 4;
#pragma unroll
      for (int r = 0; r < 4; r++) {
        int row = rowb + r;
        int b = row >> 11, m = row & 2047;
        float v = acc[i][j][r] + bc;
        if (isV)
          Vt[((((size_t)b * NHEAD + h) * HD) + d) * MM + m] = f2b(v);
        else
          Kh[(((size_t)b * NHEAD + h) * MM + m) * HD + d] = f2b(v);
      }
    }
  }
}

// ---------------- 64x64 bf16 MFMA GEMM for FFN (depth-2, 3 buffers, slot swizzle) ------------
template <bool RELU, bool OUTF32>
__global__ __launch_bounds__(256) void k_gemm64(
    const uint16_t* __restrict__ A, const uint16_t* __restrict__ Bt,
    const float* __restrict__ bias, void* __restrict__ Cv, int K, int N) {
  __shared__ __align__(16) uint16_t As[3 * 2048];
  __shared__ __align__(16) uint16_t Bs[3 * 2048];
  int tid = threadIdx.x;
  int w = tid >> 6, l = tid & 63;
  int m0 = blockIdx.y * 64, n0 = blockIdx.x * 64;
  int wm = (w >> 1) * 32, wn = (w & 1) * 32;
  f32x4 zero4 = {0.f, 0.f, 0.f, 0.f};
  f32x4 acc[2][2];
#pragma unroll
  for (int i = 0; i < 2; i++)
#pragma unroll
    for (int j = 0; j < 2; j++) acc[i][j] = zero4;

  int sr = tid >> 2;
  int xs8 = (((tid & 3) ^ ((tid >> 3) & 3))) * 8;
  const uint16_t* gA = A + (size_t)(m0 + sr) * K + xs8;
  const uint16_t* gB = Bt + (size_t)(n0 + sr) * K + xs8;
  int lm = l & 15, q = l >> 4;
  int qp = (q ^ ((lm >> 1) & 3)) * 8;

  auto stage = [&](int buf, int kt) {
    glds16(gA + kt, As + buf * 2048 + w * 512);
    glds16(gB + kt, Bs + buf * 2048 + w * 512);
  };
  auto compute = [&](int buf) {
    const uint16_t* as = As + buf * 2048;
    const uint16_t* bs = Bs + buf * 2048;
    bf16x8 af[2], bfv[2];
#pragma unroll
    for (int i = 0; i < 2; i++) {
      af[i] = *(const bf16x8*)&as[(wm + i * 16 + lm) * 32 + qp];
      bfv[i] = *(const bf16x8*)&bs[(wn + i * 16 + lm) * 32 + qp];
    }
#pragma unroll
    for (int i = 0; i < 2; i++)
#pragma unroll
      for (int j = 0; j < 2; j++)
        acc[i][j] = __builtin_amdgcn_mfma_f32_16x16x32_bf16(af[i], bfv[j], acc[i][j], 0, 0, 0);
  };

  const int NT = K / 32;
  stage(0, 0);
  stage(1, 32);
  int cur = 0;
  for (int t = 0; t < NT - 1; ++t) {
    asm volatile("s_waitcnt vmcnt(2)" ::: "memory");
    __builtin_amdgcn_s_barrier();
    if (t + 2 < NT) {
      int sb = cur + 2; if (sb >= 3) sb -= 3;
      stage(sb, (t + 2) * 32);
    }
    compute(cur);
    cur = (cur == 2) ? 0 : cur + 1;
  }
  asm volatile("s_waitcnt vmcnt(0)" ::: "memory");
  __builtin_amdgcn_s_barrier();
  compute(cur);

#pragma unroll
  for (int j = 0; j < 2; j++) {
    int col = n0 + wn + j * 16 + lm;
    float bc = bias[col];
#pragma unroll
    for (int i = 0; i < 2; i++) {
      int rowb = m0 + wm + i * 16 + q * 4;
#pragma unroll
      for (int r = 0; r < 4; r++) {
        float v = acc[i][j][r] + bc;
        if (RELU) v = fmaxf(v, 0.f);
        if (OUTF32)
          ((float*)Cv)[(size_t)(rowb + r) * N + col] = v;
        else
          ((uint16_t*)Cv)[(size_t)(rowb + r) * N + col] = f2b(v);
      }
    }
  }
}

// ---------------- grouped Q projection (slot swizzle) ----------------
__global__ __launch_bounds__(256) void k_gemm_q(
    const uint16_t* __restrict__ Xb, const uint16_t* __restrict__ WQt,
    const float* __restrict__ bQ, float* __restrict__ Q) {
  __shared__ __align__(16) uint16_t As[32 * 32];
  __shared__ __align__(16) uint16_t Bs[64 * 32];
  int tid = threadIdx.x;
  int w = tid >> 6, l = tid & 63;
  int t = blockIdx.y, n0 = blockIdx.x * 64;
  const uint16_t* Wt = WQt + (size_t)t * QD * QD;
  f32x4 zero4 = {0.f, 0.f, 0.f, 0.f};
  f32x4 acc[2] = {zero4, zero4};
  int sr = tid >> 2;
  int xs8 = (((tid & 3) ^ ((tid >> 3) & 3))) * 8;
  const uint16_t* gA = Xb + ((size_t)(sr * TT + t)) * QD + xs8;
  const uint16_t* gB = Wt + (size_t)(n0 + sr) * QD + xs8;
  int lm = l & 15, q = l >> 4;
  int qp = (q ^ ((lm >> 1) & 3)) * 8;
  for (int kt = 0; kt < QD; kt += 32) {
    __syncthreads();
    if (tid < 128) glds16(gA + kt, As + w * 512);
    glds16(gB + kt, Bs + w * 512);
    __syncthreads();
    bf16x8 bfv = *(const bf16x8*)&Bs[(w * 16 + lm) * 32 + qp];
#pragma unroll
    for (int i = 0; i < 2; i++) {
      bf16x8 af = *(const bf16x8*)&As[(i * 16 + lm) * 32 + qp];
      acc[i] = __builtin_amdgcn_mfma_f32_16x16x32_bf16(af, bfv, acc[i], 0, 0, 0);
    }
  }
  int col = n0 + w * 16 + lm;
  float bc = bQ[t * QD + col];
#pragma unroll
  for (int i = 0; i < 2; i++) {
    int b0 = i * 16 + q * 4;
#pragma unroll
    for (int r = 0; r < 4; r++) {
      int b = b0 + r;
      Q[((size_t)(b * TT + t)) * QD + col] = acc[i][r] + bc;
    }
  }
}

// ---------------- scores + softmax -> attn_w ----------------
// grid (tg=2, h=12, b=32), block 256. K rows consumed whole (L1-friendly).
__global__ __launch_bounds__(256) void k_scores(
    const float* __restrict__ Q,      // [448][768]
    const uint16_t* __restrict__ Kh,  // [b][h][m][64]
    float* __restrict__ AW) {         // [B][T][H][M]
  __shared__ __align__(16) float Qs[7][64];
  __shared__ float redv[4];
  int tid = threadIdx.x;
  int tg = blockIdx.x, h = blockIdx.y, b = blockIdx.z;
  int t0 = tg * 7;
  for (int i = tid; i < 7 * 64; i += 256) {
    int t = i >> 6, d = i & 63;
    Qs[t][d] = Q[((size_t)(b * TT + t0 + t)) * QD + h * HD + d] * 0.125f;
  }
  __syncthreads();
  float acc[7][8];
#pragma unroll
  for (int t = 0; t < 7; t++)
#pragma unroll
    for (int c = 0; c < 8; c++) acc[t][c] = 0.f;

  const uint16_t* kb = Kh + ((size_t)(b * NHEAD + h)) * MM * HD;
  for (int c = 0; c < 8; c++) {
    const uint16_t* kr = kb + (size_t)(c * 256 + tid) * HD;
#pragma unroll
    for (int dv = 0; dv < 8; dv++) {
      uint4 u = *(const uint4*)(kr + dv * 8);
      float kf[8];
      kf[0] = __uint_as_float(u.x << 16); kf[1] = __uint_as_float(u.x & 0xffff0000u);
      kf[2] = __uint_as_float(u.y << 16); kf[3] = __uint_as_float(u.y & 0xffff0000u);
      kf[4] = __uint_as_float(u.z << 16); kf[5] = __uint_as_float(u.z & 0xffff0000u);
      kf[6] = __uint_as_float(u.w << 16); kf[7] = __uint_as_float(u.w & 0xffff0000u);
#pragma unroll
      for (int t = 0; t < 7; t++) {
        float4 qa = *(const float4*)&Qs[t][dv * 8];
        float4 qb = *(const float4*)&Qs[t][dv * 8 + 4];
        float s = acc[t][c];
        s = fmaf(kf[0], qa.x, s); s = fmaf(kf[1], qa.y, s);
        s = fmaf(kf[2], qa.z, s); s = fmaf(kf[3], qa.w, s);
        s = fmaf(kf[4], qb.x, s); s = fmaf(kf[5], qb.y, s);
        s = fmaf(kf[6], qb.z, s); s = fmaf(kf[7], qb.w, s);
        acc[t][c] = s;
      }
    }
  }
  // softmax per t over 2048
  int lane = tid & 63, w = tid >> 6;
#pragma unroll
  for (int t = 0; t < 7; t++) {
    float mx = acc[t][0];
#pragma unroll
    for (int c = 1; c < 8; c++) mx = fmaxf(mx, acc[t][c]);
#pragma unroll
    for (int o = 32; o > 0; o >>= 1) mx = fmaxf(mx, __shfl_xor(mx, o));
    if (lane == 0) redv[w] = mx;
    __syncthreads();
    mx = fmaxf(fmaxf(redv[0], redv[1]), fmaxf(redv[2], redv[3]));
    __syncthreads();
    float s = 0.f;
#pragma unroll
    for (int c = 0; c < 8; c++) {
      float e = __expf(acc[t][c] - mx);
      acc[t][c] = e;
      s += e;
    }
#pragma unroll
    for (int o = 32; o > 0; o >>= 1) s += __shfl_xor(s, o);
    if (lane == 0) redv[w] = s;
    __syncthreads();
    s = redv[0] + redv[1] + redv[2] + redv[3];
    __syncthreads();
    float inv = 1.f / s;
    size_t rowb = ((size_t)((b * TT + t0 + t) * NHEAD + h)) * MM;
#pragma unroll
    for (int c = 0; c < 8; c++) AW[rowb + c * 256 + tid] = acc[t][c] * inv;
  }
}

// ---------------- partial attn_out = attn_w @ V over m-chunks ----------------
// grid (12, 32, 8), block 256. Partials reduced inside k_add_ln<8>.
__global__ __launch_bounds__(256) void k_attnout(
    const float* __restrict__ AW, const uint16_t* __restrict__ Vt,
    float* __restrict__ pbuf) {
  int tid = threadIdx.x;
  int h = blockIdx.x, b = blockIdx.y, mc = blockIdx.z;
  int d = tid & 63, tg = tid >> 6;
  int m0 = mc * 256;
  const uint16_t* vr = Vt + (((size_t)(b * NHEAD + h)) * HD + d) * MM + m0;
  const float* pb = AW + ((size_t)(b * TT * NHEAD + h)) * MM + m0;
  float acc[4] = {0.f, 0.f, 0.f, 0.f};
#pragma unroll 2
  for (int mcc = 0; mcc < 256; mcc += 8) {
    uint4 u = *(const uint4*)(vr + mcc);
    float vf[8];
    vf[0] = __uint_as_float(u.x << 16); vf[1] = __uint_as_float(u.x & 0xffff0000u);
    vf[2] = __uint_as_float(u.y << 16); vf[3] = __uint_as_float(u.y & 0xffff0000u);
    vf[4] = __uint_as_float(u.z << 16); vf[5] = __uint_as_float(u.z & 0xffff0000u);
    vf[6] = __uint_as_float(u.w << 16); vf[7] = __uint_as_float(u.w & 0xffff0000u);
#pragma unroll
    for (int i = 0; i < 4; i++) {
      int t = tg * 4 + i;
      if (t < TT) {
        const float* pr = pb + (size_t)t * NHEAD * MM + mcc;
        float4 p0 = *(const float4*)pr;
        float4 p1 = *(const float4*)(pr + 4);
        float s = acc[i];
        s = fmaf(vf[0], p0.x, s); s = fmaf(vf[1], p0.y, s);
        s = fmaf(vf[2], p0.z, s); s = fmaf(vf[3], p0.w, s);
        s = fmaf(vf[4], p1.x, s); s = fmaf(vf[5], p1.y, s);
        s = fmaf(vf[6], p1.z, s); s = fmaf(vf[7], p1.w, s);
        acc[i] = s;
      }
    }
  }
#pragma unroll
  for (int i = 0; i < 4; i++) {
    int t = tg * 4 + i;
    if (t < TT)
      pbuf[(size_t)mc * CHSTRIDE + ((size_t)(b * TT + t)) * QD + h * HD + d] = acc[i];
  }
}

// ---------------- add + layernorm (with NCHUNK-way partial reduce of Y) ----------------
template <int NCHUNK>
__global__ __launch_bounds__(256) void k_add_ln(
    const float* __restrict__ X, const float* __restrict__ P,
    const float* __restrict__ g, const float* __restrict__ be,
    float* __restrict__ outF, uint16_t* __restrict__ outB) {
  __shared__ float redS[4], redQ[4];
  int r = blockIdx.x, tid = threadIdx.x;
  size_t base = (size_t)r * QD;
  float e[3];
  float s = 0.f, sq = 0.f;
#pragma unroll
  for (int j = 0; j < 3; j++) {
    int i = tid + j * 256;
    float v = X[base + i];
#pragma unroll
    for (int c = 0; c < NCHUNK; c++) v += P[(size_t)c * CHSTRIDE + base + i];
    e[j] = v; s += v; sq += v * v;
  }
#pragma unroll
  for (int o = 32; o > 0; o >>= 1) { s += __shfl_xor(s, o); sq += __shfl_xor(sq, o); }
  if ((tid & 63) == 0) { redS[tid >> 6] = s; redQ[tid >> 6] = sq; }
  __syncthreads();
  s = redS[0] + redS[1] + redS[2] + redS[3];
  sq = redQ[0] + redQ[1] + redQ[2] + redQ[3];
  float mu = s * (1.f / QD);
  float var = sq * (1.f / QD) - mu * mu;
  float rstd = rsqrtf(var + 1e-5f);
#pragma unroll
  for (int j = 0; j < 3; j++) {
    int i = tid + j * 256;
    float v = (e[j] - mu) * rstd * g[i] + be[i];
    outF[base + i] = v;
    if (outB) outB[base + i] = f2b(v);
  }
}

extern "C" void kernel_launch(void* const* d_in, const int* in_sizes, int n_in,
                              void* d_out, int out_size, void* d_ws, size_t ws_size,
                              hipStream_t stream) {
  const float* tok = (const float*)d_in[0];
  const float* kve = (const float*)d_in[1];
  const float* WQ  = (const float*)d_in[2];
  const float* bQ  = (const float*)d_in[3];
  const float* WK  = (const float*)d_in[4];
  const float* bK  = (const float*)d_in[5];
  const float* WV  = (const float*)d_in[6];
  const float* bV  = (const float*)d_in[7];
  const float* W1  = (const float*)d_in[8];
  const float* b1  = (const float*)d_in[9];
  const float* W2  = (const float*)d_in[10];
  const float* b2  = (const float*)d_in[11];
  const float* g1  = (const float*)d_in[12];
  const float* be1 = (const float*)d_in[13];
  const float* g2  = (const float*)d_in[14];
  const float* be2 = (const float*)d_in[15];

  float* outp = (float*)d_out;            // [448][768]
  float* AW = outp + 448 * 768;           // [32][14][12][2048]

  char* p = (char*)d_ws;
  auto nxt = [&](size_t bytes) -> char* {
    char* r = p;
    p += (bytes + 255) & ~(size_t)255;
    return r;
  };
  uint16_t* Abf   = (uint16_t*)nxt((size_t)67108864 * 2);   // KV embeddings bf16
  uint16_t* Kh    = (uint16_t*)nxt((size_t)50331648 * 2);   // [32][12][2048][64]
  uint16_t* Vt    = (uint16_t*)nxt((size_t)50331648 * 2);   // [32][12][64][2048]
  uint16_t* Wkvt  = (uint16_t*)nxt((size_t)1572864 * 2);    // [1536][1024]
  uint16_t* WQt   = (uint16_t*)nxt((size_t)8257536 * 2);    // [14][768][768]
  uint16_t* W1t   = (uint16_t*)nxt((size_t)2359296 * 2);    // [3072][768]
  uint16_t* W2t   = (uint16_t*)nxt((size_t)2359296 * 2);    // [768][3072]
  uint16_t* xtokb = (uint16_t*)nxt((size_t)344064 * 2);     // tokens bf16
  float* biaskv   = (float*)nxt(1536 * 4);
  float* Qws      = (float*)nxt((size_t)344064 * 4);
  float* pbuf     = (float*)nxt((size_t)8 * CHSTRIDE * 4);  // attn_out partials
  float* xws      = (float*)nxt((size_t)344064 * 4);
  uint16_t* xbf   = (uint16_t*)nxt((size_t)344064 * 2);
  uint16_t* h1bf  = (uint16_t*)nxt((size_t)1376256 * 2);    // [448][3072]
  float* yws      = (float*)nxt((size_t)344064 * 4);

  // conversions
  k_cast8<<<dim3(32768), dim3(256), 0, stream>>>((const float4*)kve, (uint4*)Abf);
  k_cast8<<<dim3(168), dim3(256), 0, stream>>>((const float4*)tok, (uint4*)xtokb);
  k_transpose_bf16<<<dim3(24, 32, 1), dim3(256), 0, stream>>>(WK, Wkvt, 1024, 768);
  k_transpose_bf16<<<dim3(24, 32, 1), dim3(256), 0, stream>>>(WV, Wkvt + (size_t)768 * 1024, 1024, 768);
  k_transpose_bf16<<<dim3(24, 24, 14), dim3(256), 0, stream>>>(WQ, WQt, 768, 768);
  k_transpose_bf16<<<dim3(96, 24, 1), dim3(256), 0, stream>>>(W1, W1t, 768, 3072);
  k_transpose_bf16<<<dim3(24, 96, 1), dim3(256), 0, stream>>>(W2, W2t, 3072, 768);
  k_bias_concat<<<dim3(6), dim3(256), 0, stream>>>(bK, bV, biaskv);

  // K|V projection -> head-major K, transposed V  (256x256 tiles, 8-phase)
  k_gemm_kv<<<dim3(6, 256), dim3(512), 0, stream>>>(Abf, Wkvt, biaskv, Kh, Vt);

  // Q projection (per-t grouped)
  k_gemm_q<<<dim3(12, 14), dim3(256), 0, stream>>>(xtokb, WQt, bQ, Qws);

  // scores + softmax -> attn_w (f32, second output)
  k_scores<<<dim3(2, 12, 32), dim3(256), 0, stream>>>(Qws, Kh, AW);

  // attn_out partials over 8 m-chunks (latency-hiding via 3072 blocks)
  k_attnout<<<dim3(12, 32, 8), dim3(256), 0, stream>>>(AW, Vt, pbuf);

  // x = LN(tok + sum_mc pbuf[mc])
  k_add_ln<8><<<dim3(448), dim3(256), 0, stream>>>(tok, pbuf, g1, be1, xws, xbf);

  // FFN
  k_gemm64<true, false><<<dim3(48, 7), dim3(256), 0, stream>>>(xbf, W1t, b1, (void*)h1bf, 768, 3072);
  k_gemm64<false, true><<<dim3(12, 7), dim3(256), 0, stream>>>(h1bf, W2t, b2, (void*)yws, 3072, 768);

  // out = LN(x + ff)
  k_add_ln<1><<<dim3(448), dim3(256), 0, stream>>>(xws, yws, g2, be2, outp, (uint16_t*)nullptr);
}